// Round 15
// baseline (996.312 us; speedup 1.0000x reference)
//
#include <hip/hip_runtime.h>

#define B_    16
#define CIN_  512
#define CF_   64
#define FH_   11
#define FW_   20
#define N_    2784
#define NM1_  2783
#define PK_   2816
#define D_    704
#define D2_   1408
#define ROWS_ 44544
#define PW_   77

// ---- input element counts
#define NX_     1802240
#define NCW_    32768
#define NCB_    64
#define NATTW_  1959232
#define NATTB_  2783
#define NCLSW_  2816
#define NCLSB_  2
#define NREGW_  102784
#define NREGB_  73
#define NANCH_  214368
#define NCUT_   30624

// ---- canonical ws layout (byte offsets)
#define OFF_FLAGS   0u
#define OFF_FEAT    256u
#define OFF_CANON   (1u<<20)
#define C_X      0u
#define C_ATTW   3604480u
#define C_CW     7522944u
#define C_ANCH   7588480u
#define C_CLSW   8017216u
#define C_REGW   8022848u
#define C_CB     8228416u
#define C_ATTB   8228544u
#define C_CLSB   8234112u
#define C_REGB   8234128u
#define C_CUT    8234288u
#define C_MASK   8356784u

typedef __bf16 bf16x8 __attribute__((ext_vector_type(8)));
typedef float  f32x4  __attribute__((ext_vector_type(4)));

typedef __attribute__((address_space(1))) void g_void;
typedef __attribute__((address_space(3))) void l_void;
#define GLD16(gp, lp) __builtin_amdgcn_global_load_lds((g_void*)(gp), (l_void*)(lp), 16, 0, 0)

// row permutation + chunk swizzle for 64B-row K-half LDS tiles (conflict-free derivation r15)
#define PHYS(R)  ((((R) & 1) << 7) | ((R) >> 1))
#define GLOB(P)  ((((P) & 127) << 1) | ((P) >> 7))
#define G2P(P)   (((P) + ((P) >> 1)) & 3)

__device__ __forceinline__ float bf2f(unsigned short u) {
    union { unsigned int u; float f; } v; v.u = ((unsigned int)u) << 16; return v.f;
}
__device__ __forceinline__ unsigned short f2bf(float f) {
    union { float f; unsigned int u; } v; v.f = f;
    unsigned int x = v.u;
    return (unsigned short)((x + 0x7FFFu + ((x >> 16) & 1u)) >> 16);
}

// m204 bijective XCD swizzle
__device__ __forceinline__ int swz8(int olid, int nwg) {
    int xcd = olid & 7, pos = olid >> 3;
    int q = nwg >> 3, r = nwg & 7;
    int off = (xcd < r) ? xcd * (q + 1) : r * (q + 1) + (xcd - r) * q;
    return off + pos;
}

// ---------------- K0: dtype detection
__global__ __launch_bounds__(256) void k_detect(const unsigned int* __restrict__ attw,
                                                const unsigned int* __restrict__ cut,
                                                const unsigned int* __restrict__ msk,
                                                int* __restrict__ flags) {
    __shared__ int cnt[3];
    int t = threadIdx.x;
    if (t < 3) cnt[t] = 0;
    __syncthreads();
    int c0 = 0, c1 = 0, c2 = 0;
    for (int i = t; i < 2048; i += 256) {
        unsigned int e = (attw[i] >> 7) & 0xFFu;
        if (e >= 127u) c0++;
    }
    for (int i = t; i < 4096; i += 256) if (cut[i] >= 32u) c1++;
    for (int i = t; i < 4096; i += 256) if (msk[i] >= 2u)  c2++;
    atomicAdd(&cnt[0], c0); atomicAdd(&cnt[1], c1); atomicAdd(&cnt[2], c2);
    __syncthreads();
    if (t == 0) {
        flags[0] = cnt[0] > 64;
        flags[1] = cnt[1] > 64;
        flags[2] = cnt[2] > 64;
        flags[3] = 0;
    }
}

// ---------------- K0b: canonicalize float inputs to bf16
__device__ __forceinline__ void cvt_arr(const void* s, unsigned short* d, int n, int isf32,
                                        int tid, int stride) {
    if (isf32) {
        const float* p = (const float*)s;
        for (int i = tid; i < n; i += stride) d[i] = f2bf(p[i]);
    } else {
        const unsigned short* p = (const unsigned short*)s;
        for (int i = tid; i < n; i += stride) d[i] = p[i];
    }
}

__global__ __launch_bounds__(256) void k_canon_f(const void* sx, const void* scw, const void* scb,
                                                 const void* sattw, const void* sattb,
                                                 const void* sclsw, const void* sclsb,
                                                 const void* sregw, const void* sregb,
                                                 const void* sanch, char* canon,
                                                 const int* __restrict__ flags) {
    const int isf32 = flags[0];
    const int tid = blockIdx.x * 256 + threadIdx.x;
    const int stride = gridDim.x * 256;
    cvt_arr(sx,    (unsigned short*)(canon + C_X),    NX_,    isf32, tid, stride);
    cvt_arr(sattw, (unsigned short*)(canon + C_ATTW), NATTW_, isf32, tid, stride);
    cvt_arr(scw,   (unsigned short*)(canon + C_CW),   NCW_,   isf32, tid, stride);
    cvt_arr(sanch, (unsigned short*)(canon + C_ANCH), NANCH_, isf32, tid, stride);
    cvt_arr(sclsw, (unsigned short*)(canon + C_CLSW), NCLSW_, isf32, tid, stride);
    cvt_arr(sregw, (unsigned short*)(canon + C_REGW), NREGW_, isf32, tid, stride);
    cvt_arr(scb,   (unsigned short*)(canon + C_CB),   NCB_,   isf32, tid, stride);
    cvt_arr(sattb, (unsigned short*)(canon + C_ATTB), NATTB_, isf32, tid, stride);
    cvt_arr(sclsb, (unsigned short*)(canon + C_CLSB), NCLSB_, isf32, tid, stride);
    cvt_arr(sregb, (unsigned short*)(canon + C_REGB), NREGB_, isf32, tid, stride);
}

// ---------------- K0c: canonicalize int inputs to int32
__global__ __launch_bounds__(256) void k_canon_i(const void* scut, const void* smsk,
                                                 char* canon, const int* __restrict__ flags) {
    const int cutb = flags[1], mskb = flags[2];
    int* ccut = (int*)(canon + C_CUT);
    int* cmsk = (int*)(canon + C_MASK);
    const int tid = blockIdx.x * 256 + threadIdx.x;
    const int stride = gridDim.x * 256;
    for (int i = tid; i < NCUT_; i += stride) {
        ccut[i] = cutb ? (int)((const unsigned char*)scut)[i] : ((const int*)scut)[i];
        int m = mskb ? (int)((const unsigned char*)smsk)[i] : ((const int*)smsk)[i];
        cmsk[i] = (m != 0);
    }
}

// ---------------- K1: 1x1 conv
__global__ __launch_bounds__(256) void k_conv(const unsigned short* __restrict__ x,
                                              const unsigned short* __restrict__ cw,
                                              const unsigned short* __restrict__ cb,
                                              float* __restrict__ feat) {
    int idx = blockIdx.x * 256 + threadIdx.x;
    int w = idx % FW_;
    int h = (idx / FW_) % FH_;
    int o = (idx / (FW_ * FH_)) % CF_;
    int b = idx / (FW_ * FH_ * CF_);
    const unsigned short* xp = x + ((size_t)(b * CIN_) * FH_ + h) * FW_ + w;
    const unsigned short* wp = cw + (size_t)o * CIN_;
    float acc = bf2f(cb[o]);
#pragma unroll 8
    for (int c = 0; c < CIN_; ++c)
        acc += bf2f(xp[(size_t)c * (FH_ * FW_)]) * bf2f(wp[c]);
    feat[idx] = acc;
}

// ---------------- K2a: AF chunk
__global__ __launch_bounds__(256) void k_gather_af(const float* __restrict__ feat,
                                                   const int* __restrict__ cut,
                                                   const int* __restrict__ inv,
                                                   unsigned short* __restrict__ AF,
                                                   int batch_base) {
    int n = blockIdx.x, bl = blockIdx.y;
    int b = batch_base + bl;
    __shared__ int cu[FH_];
    __shared__ int iv[FH_];
    int t = threadIdx.x;
    if (t < FH_) { cu[t] = cut[n * FH_ + t]; iv[t] = inv[n * FH_ + t]; }
    __syncthreads();
    unsigned short* out = AF + ((size_t)(bl * N_ + n)) * D_;
    for (int d = t; d < D_; d += 256) {
        int c = d / FH_, h = d - c * FH_;
        float v = iv[h] ? 0.f : feat[((b * CF_ + c) * FH_ + h) * FW_ + cu[h]];
        out[d] = f2bf(v);
    }
}

// ---------------- K2b: AFT chunk (stride PK_, pad cols zeroed)
__global__ __launch_bounds__(256) void k_gather_aft(const float* __restrict__ feat,
                                                    const int* __restrict__ cut,
                                                    const int* __restrict__ inv,
                                                    unsigned short* __restrict__ AFT,
                                                    int batch_base) {
    int d = blockIdx.x, bl = blockIdx.y;
    int b = batch_base + bl;
    int c = d / FH_, h = d - c * FH_;
    const float* fp = feat + ((b * CF_ + c) * FH_ + h) * FW_;
    unsigned short* out = AFT + ((size_t)(bl * D_ + d)) * PK_;
    for (int n = threadIdx.x; n < PK_; n += 256) {
        float v = 0.f;
        if (n < N_) {
            int w = cut[n * FH_ + h];
            v = inv[n * FH_ + h] ? 0.f : fp[w];
        }
        out[n] = f2bf(v);
    }
}

// ======== shared 8-phase GEMM body (256^2 tile, 512 thr, 8 waves 2x4, BK=64) ========
// LDS per matrix: [2 buf][2 khalf][256 phys-rows x 32 K]; physical row P holds global
// row GLOB(P); chunk c holds logical chunk c ^ G2P(P). Read offsets precomputed.

#define GEMM_PROLOGUE()                                                               \
    STAGE_A(0, 0, 0); STAGE_B(0, 0, 0); STAGE_A(0, 1, 0); STAGE_B(0, 1, 0);           \
    STAGE_A(1, 0, 1); STAGE_B(1, 0, 1);

#define RD_A(kh)                                                                      \
    _Pragma("unroll")                                                                 \
    for (int m = 0; m < 8; ++m)                                                       \
        a[m] = *(const bf16x8*)(As + cur * 16384 + (kh) * 8192 + aoff[m]);

#define RD_B(kh, n0)                                                                  \
    {                                                                                 \
        b0 = *(const bf16x8*)(Bs + cur * 16384 + (kh) * 8192 + boff[(n0)]);           \
        b1 = *(const bf16x8*)(Bs + cur * 16384 + (kh) * 8192 + boff[(n0) + 1]);       \
    }

#define MFMA16(n0)                                                                    \
    asm volatile("s_waitcnt lgkmcnt(0)" ::: "memory");                                \
    __builtin_amdgcn_sched_barrier(0);                                                \
    __builtin_amdgcn_s_setprio(1);                                                    \
    _Pragma("unroll")                                                                 \
    for (int m = 0; m < 8; ++m) {                                                     \
        acc[m][(n0)] = __builtin_amdgcn_mfma_f32_16x16x32_bf16(a[m], b0, acc[m][(n0)], 0, 0, 0); \
        acc[m][(n0) + 1] = __builtin_amdgcn_mfma_f32_16x16x32_bf16(a[m], b1, acc[m][(n0) + 1], 0, 0, 0); \
    }                                                                                 \
    __builtin_amdgcn_s_setprio(0);

#define BOUNDARY(tail)                                                                \
    if (tail) asm volatile("s_waitcnt vmcnt(0)" ::: "memory");                        \
    else      asm volatile("s_waitcnt vmcnt(8)" ::: "memory");                        \
    __builtin_amdgcn_sched_barrier(0);                                                \
    __builtin_amdgcn_s_barrier();

#define GEMM_LOOP(NT)                                                                 \
    for (int tt = 0; tt < (NT); ++tt) {                                               \
        const int cur = tt & 1, nxt = cur ^ 1;                                        \
        const bool tail = (tt >= (NT) - 2);                                           \
        BOUNDARY(tail);                                                               \
        RD_A(0); RD_B(0, 0);                                                          \
        if (tt + 1 < (NT)) STAGE_A(nxt, 1, tt + 1);                                   \
        MFMA16(0);                                                                    \
        __builtin_amdgcn_s_barrier();                                                 \
        RD_B(0, 2);                                                                   \
        if (tt + 1 < (NT)) STAGE_B(nxt, 1, tt + 1);                                   \
        MFMA16(2);                                                                    \
        __builtin_amdgcn_s_barrier();                                                 \
        BOUNDARY(tail);                                                               \
        RD_A(1); RD_B(1, 0);                                                          \
        if (tt + 2 < (NT)) STAGE_A(cur, 0, tt + 2);                                   \
        MFMA16(0);                                                                    \
        __builtin_amdgcn_s_barrier();                                                 \
        RD_B(1, 2);                                                                   \
        if (tt + 2 < (NT)) STAGE_B(cur, 0, tt + 2);                                   \
        MFMA16(2);                                                                    \
    }

#define MK_OFFS(nloc_rowsA, nloc_rowsB)                                               \
    int aoff[8], boff[4];                                                             \
    _Pragma("unroll")                                                                 \
    for (int m = 0; m < 8; ++m) {                                                     \
        int R = wrow * 128 + m * 16 + l15;                                            \
        int P = PHYS(R);                                                              \
        aoff[m] = P * 32 + ((hi ^ G2P(P)) * 8);                                       \
    }                                                                                 \
    _Pragma("unroll")                                                                 \
    for (int n = 0; n < 4; ++n) {                                                     \
        int R = wcol * 64 + n * 16 + l15;                                             \
        int P = PHYS(R);                                                              \
        boff[n] = P * 32 + ((hi ^ G2P(P)) * 8);                                       \
    }

// ---------------- K3a: MFMA scores GEMM (8-phase, permuted-row swizzle)
__global__ __launch_bounds__(512, 1) void k_scores(const unsigned short* __restrict__ AF,
                                                   const unsigned short* __restrict__ attw,
                                                   const unsigned short* __restrict__ attb,
                                                   unsigned short* __restrict__ Mbf,
                                                   int nloc) {
    __shared__ __bf16 As[2 * 16384];
    __shared__ __bf16 Bs[2 * 16384];
    const int t = threadIdx.x;
    const int nwg = gridDim.x * gridDim.y;
    const int olid = blockIdx.x + gridDim.x * blockIdx.y;
    const int nid = swz8(olid, nwg);
    const int jt = nid % 11, it = nid / 11;
    const int i0 = it * 256, j0 = jt * 256;
    const int lane = t & 63, wv = t >> 6;
    const int wrow = wv >> 2, wcol = wv & 3;
    const int l15 = lane & 15, hi = lane >> 4;

    f32x4 zero = {0.f, 0.f, 0.f, 0.f};
    f32x4 acc[8][4];
#pragma unroll
    for (int m = 0; m < 8; ++m)
#pragma unroll
        for (int n = 0; n < 4; ++n) acc[m][n] = zero;

    MK_OFFS(nloc, NM1_);

    // stage source bases: slot s -> physical row P=s>>2, chunk c=s&3 holds
    // logical chunk c^G2P(P) of GLOBAL row GLOB(P)
    const unsigned short *aB0, *aB1, *bB0, *bB1;
    {
        int P0 = t >> 2, P1 = (t + 512) >> 2;
        int g0 = GLOB(P0), g1 = GLOB(P1);
        int lc0 = (t & 3) ^ G2P(P0), lc1 = (t & 3) ^ G2P(P1);
        int ia0 = i0 + g0; if (ia0 > nloc - 1) ia0 = nloc - 1;
        int ia1 = i0 + g1; if (ia1 > nloc - 1) ia1 = nloc - 1;
        int jb0 = j0 + g0; if (jb0 > NM1_ - 1) jb0 = NM1_ - 1;
        int jb1 = j0 + g1; if (jb1 > NM1_ - 1) jb1 = NM1_ - 1;
        aB0 = AF + (size_t)ia0 * D_ + lc0 * 8;
        aB1 = AF + (size_t)ia1 * D_ + lc1 * 8;
        bB0 = attw + (size_t)jb0 * D_ + lc0 * 8;
        bB1 = attw + (size_t)jb1 * D_ + lc1 * 8;
    }
#define STAGE_A(buf, kh, kt) { \
    GLD16(aB0 + (kt) * 64 + (kh) * 32, As + (buf) * 16384 + (kh) * 8192 + t * 8); \
    GLD16(aB1 + (kt) * 64 + (kh) * 32, As + (buf) * 16384 + (kh) * 8192 + (t + 512) * 8); }
#define STAGE_B(buf, kh, kt) { \
    GLD16(bB0 + (kt) * 64 + (kh) * 32, Bs + (buf) * 16384 + (kh) * 8192 + t * 8); \
    GLD16(bB1 + (kt) * 64 + (kh) * 32, Bs + (buf) * 16384 + (kh) * 8192 + (t + 512) * 8); }

    bf16x8 a[8], b0, b1;
    GEMM_PROLOGUE();
    GEMM_LOOP(11);            // D_/64
#undef STAGE_A
#undef STAGE_B

#pragma unroll
    for (int m = 0; m < 8; ++m) {
        int ib = i0 + wrow * 128 + m * 16 + hi * 4;
#pragma unroll
        for (int n = 0; n < 4; ++n) {
            int j = j0 + wcol * 64 + n * 16 + l15;
            if (j < NM1_) {
                float bias = bf2f(attb[j]);
#pragma unroll
                for (int q = 0; q < 4; ++q) {
                    int ii = ib + q;
                    if (ii < nloc) {
                        int r = ii % N_;
                        int c = j + (j >= r);
                        Mbf[(size_t)ii * PK_ + c] = f2bf(acc[m][n][q] + bias);
                    }
                }
            }
        }
    }
}

// ---------------- K3b: bf16 row softmax IN PLACE (stride PK_, zero pad) + f32 M to d_out
__global__ __launch_bounds__(256) void k_softmax(unsigned short* __restrict__ Mbf,
                                                 float* __restrict__ Mout,
                                                 int row_base) {
    const int il = blockIdx.x;
    const int r = il % N_;
    unsigned short* srow = Mbf + (size_t)il * PK_;
    float* orow = Mout + (size_t)(row_base + il) * N_;
    const int t = threadIdx.x;
    float f[16];
#pragma unroll
    for (int q = 0; q < 2; ++q) {
        int c8 = t + 256 * q;
        if (c8 < N_ / 8) {
            uint4 u = *(const uint4*)(srow + c8 * 8);
            const unsigned short* pu = (const unsigned short*)&u;
#pragma unroll
            for (int e = 0; e < 8; ++e) {
                int c = c8 * 8 + e;
                float v = bf2f(pu[e]);
                f[q * 8 + e] = (c == r) ? -1e30f : v;
            }
        } else {
#pragma unroll
            for (int e = 0; e < 8; ++e) f[q * 8 + e] = -1e30f;
        }
    }
    float m = -1e30f;
#pragma unroll
    for (int q = 0; q < 16; ++q) m = fmaxf(m, f[q]);
#pragma unroll
    for (int off = 32; off >= 1; off >>= 1) m = fmaxf(m, __shfl_xor(m, off, 64));
    __shared__ float red[4];
    if ((t & 63) == 0) red[t >> 6] = m;
    __syncthreads();
    m = fmaxf(fmaxf(red[0], red[1]), fmaxf(red[2], red[3]));

    float s = 0.f;
#pragma unroll
    for (int q = 0; q < 16; ++q) { float e = __expf(f[q] - m); f[q] = e; s += e; }
#pragma unroll
    for (int off = 32; off >= 1; off >>= 1) s += __shfl_xor(s, off, 64);
    __shared__ float red2[4];
    if ((t & 63) == 0) red2[t >> 6] = s;
    __syncthreads();
    s = red2[0] + red2[1] + red2[2] + red2[3];
    float inv = 1.0f / s;
#pragma unroll
    for (int q = 0; q < 2; ++q) {
        int c8 = t + 256 * q;
        if (c8 < N_ / 8) {
            float o[8];
            union { unsigned short u[8]; uint4 v; } pb;
#pragma unroll
            for (int e = 0; e < 8; ++e) {
                o[e] = f[q * 8 + e] * inv;     // diag: exp(-1e30-m)=0 -> exact 0
                pb.u[e] = f2bf(o[e]);
            }
            float4 o0 = {o[0], o[1], o[2], o[3]};
            float4 o1 = {o[4], o[5], o[6], o[7]};
            *(float4*)(orow + c8 * 8) = o0;
            *(float4*)(orow + c8 * 8 + 4) = o1;
            *(uint4*)(srow + c8 * 8) = pb.v;
        }
    }
    if (t < 4) {
        uint4 z = {0u, 0u, 0u, 0u};
        *(uint4*)(srow + N_ + t * 8) = z;
    }
}

// ---------------- K4: MFMA att_feat = Mbf @ AF (8-phase, permuted-row swizzle)
__global__ __launch_bounds__(512, 1) void k_attgemm(const unsigned short* __restrict__ Mbf,
                                                    const unsigned short* __restrict__ AFT,
                                                    unsigned short* __restrict__ ATF) {
    __shared__ __bf16 As[2 * 16384];
    __shared__ __bf16 Bs[2 * 16384];
    const int t = threadIdx.x;
    const int nwg = gridDim.x * gridDim.y * gridDim.z;
    const int olid = blockIdx.x + gridDim.x * (blockIdx.y + gridDim.y * blockIdx.z);
    const int nid = swz8(olid, nwg);
    const int jt = nid % 3, it = (nid / 3) % 11, bl = nid / 33;
    const int i0 = it * 256, j0 = jt * 256;
    const int lane = t & 63, wv = t >> 6;
    const int wrow = wv >> 2, wcol = wv & 3;
    const int l15 = lane & 15, hi = lane >> 4;

    f32x4 zero = {0.f, 0.f, 0.f, 0.f};
    f32x4 acc[8][4];
#pragma unroll
    for (int m = 0; m < 8; ++m)
#pragma unroll
        for (int n = 0; n < 4; ++n) acc[m][n] = zero;

    MK_OFFS(N_, D_);

    const unsigned short *aB0, *aB1, *bB0, *bB1;
    {
        int P0 = t >> 2, P1 = (t + 512) >> 2;
        int g0 = GLOB(P0), g1 = GLOB(P1);
        int lc0 = (t & 3) ^ G2P(P0), lc1 = (t & 3) ^ G2P(P1);
        int ia0 = i0 + g0; if (ia0 > N_ - 1) ia0 = N_ - 1;
        int ia1 = i0 + g1; if (ia1 > N_ - 1) ia1 = N_ - 1;
        int jb0 = j0 + g0; if (jb0 > D_ - 1) jb0 = D_ - 1;
        int jb1 = j0 + g1; if (jb1 > D_ - 1) jb1 = D_ - 1;
        aB0 = Mbf + ((size_t)bl * N_ + ia0) * PK_ + lc0 * 8;
        aB1 = Mbf + ((size_t)bl * N_ + ia1) * PK_ + lc1 * 8;
        bB0 = AFT + ((size_t)bl * D_ + jb0) * PK_ + lc0 * 8;
        bB1 = AFT + ((size_t)bl * D_ + jb1) * PK_ + lc1 * 8;
    }
#define STAGE_A(buf, kh, kt) { \
    GLD16(aB0 + (kt) * 64 + (kh) * 32, As + (buf) * 16384 + (kh) * 8192 + t * 8); \
    GLD16(aB1 + (kt) * 64 + (kh) * 32, As + (buf) * 16384 + (kh) * 8192 + (t + 512) * 8); }
#define STAGE_B(buf, kh, kt) { \
    GLD16(bB0 + (kt) * 64 + (kh) * 32, Bs + (buf) * 16384 + (kh) * 8192 + t * 8); \
    GLD16(bB1 + (kt) * 64 + (kh) * 32, Bs + (buf) * 16384 + (kh) * 8192 + (t + 512) * 8); }

    bf16x8 a[8], b0, b1;
    GEMM_PROLOGUE();
    GEMM_LOOP(44);            // PK_/64
#undef STAGE_A
#undef STAGE_B

#pragma unroll
    for (int m = 0; m < 8; ++m) {
        int rb = i0 + wrow * 128 + m * 16 + hi * 4;
#pragma unroll
        for (int n = 0; n < 4; ++n) {
            int d = j0 + wcol * 64 + n * 16 + l15;
            if (d < D_) {
#pragma unroll
                for (int q = 0; q < 4; ++q) {
                    int rr = rb + q;
                    if (rr < N_)
                        ATF[((size_t)(bl * N_ + rr)) * D_ + d] = f2bf(acc[m][n][q]);
                }
            }
        }
    }
}

// ---------------- K5: MFMA heads + fused props epilogue (f32 out)
__global__ __launch_bounds__(256) void k_head(const unsigned short* __restrict__ ATF,
                                              const unsigned short* __restrict__ AF,
                                              const unsigned short* __restrict__ clsw,
                                              const unsigned short* __restrict__ clsb,
                                              const unsigned short* __restrict__ regw,
                                              const unsigned short* __restrict__ regb,
                                              const unsigned short* __restrict__ anch,
                                              float* __restrict__ props,
                                              int row_base, int nloc) {
    __shared__ __bf16 As2[128 * 32];
    __shared__ __bf16 Ws[80 * 32];
    const int t = threadIdx.x;
    const int i0 = blockIdx.x * 128;
    const int lane = t & 63, wv = t >> 6;
    const int l15 = lane & 15, hi8 = (lane >> 4) * 8;

    f32x4 zero = {0.f, 0.f, 0.f, 0.f};
    f32x4 acc[2][5];
#pragma unroll
    for (int m = 0; m < 2; ++m)
#pragma unroll
        for (int n = 0; n < 5; ++n) acc[m][n] = zero;

    const int s0 = t, s1 = t + 256;
    const int ar0 = s0 >> 2, ac0 = (s0 & 3) * 8;
    const int ar1 = s1 >> 2, ac1 = (s1 & 3) * 8;
    int ir0 = i0 + ar0; if (ir0 > nloc - 1) ir0 = nloc - 1;
    int ir1 = i0 + ar1; if (ir1 > nloc - 1) ir1 = nloc - 1;
    const unsigned short* w0base = (ar0 < 2) ? (clsw + (size_t)ar0 * D2_)
                                             : (regw + (size_t)(ar0 - 2) * D2_);
    int r1 = 64 + (t >> 2);
    int rc = r1 < 75 ? r1 : 74;
    const unsigned short* w1base = regw + (size_t)(rc - 2) * D2_;
    const int w1c = (t & 3) * 8;

    for (int p = 0; p < 2; ++p) {
        const unsigned short* Asrc = (p == 0) ? ATF : AF;
        const int wcol = p * D_;
        for (int k0 = 0; k0 < D_; k0 += 32) {
            GLD16(Asrc + (size_t)ir0 * D_ + ac0 + k0, As2 + s0 * 8);
            GLD16(Asrc + (size_t)ir1 * D_ + ac1 + k0, As2 + s1 * 8);
            GLD16(w0base + wcol + k0 + ac0, Ws + s0 * 8);
            if (t < 64) GLD16(w1base + wcol + k0 + w1c, Ws + (size_t)(256 + t) * 8);
            __syncthreads();
            bf16x8 a[2], bb[5];
#pragma unroll
            for (int m = 0; m < 2; ++m)
                a[m] = *(const bf16x8*)(As2 + (wv * 32 + m * 16 + l15) * 32 + hi8);
#pragma unroll
            for (int n = 0; n < 5; ++n)
                bb[n] = *(const bf16x8*)(Ws + (n * 16 + l15) * 32 + hi8);
#pragma unroll
            for (int m = 0; m < 2; ++m)
#pragma unroll
                for (int n = 0; n < 5; ++n)
                    acc[m][n] = __builtin_amdgcn_mfma_f32_16x16x32_bf16(a[m], bb[n], acc[m][n], 0, 0, 0);
            __syncthreads();
        }
    }

#pragma unroll
    for (int m = 0; m < 2; ++m) {
        int ib = i0 + wv * 32 + m * 16 + (lane >> 4) * 4;
#pragma unroll
        for (int n = 0; n < 5; ++n) {
            int j = n * 16 + l15;
            if (j < 75) {
#pragma unroll
                for (int q = 0; q < 4; ++q) {
                    int i = ib + q;
                    if (i < nloc) {
                        size_t g = (size_t)(row_base + i);
                        int nn = i % N_;
                        float v = acc[m][n][q];
                        if (j < 2) {
                            props[g * PW_ + j] = v + bf2f(clsb[j]);
                            props[g * PW_ + 2 + j] = bf2f(anch[(size_t)nn * PW_ + 2 + j]);
                        } else {
                            int tt = j - 2;
                            props[g * PW_ + 4 + tt] = v + bf2f(regb[tt]) + bf2f(anch[(size_t)nn * PW_ + 4 + tt]);
                        }
                    }
                }
            }
        }
    }
}

extern "C" void kernel_launch(void* const* d_in, const int* in_sizes, int n_in,
                              void* d_out, int out_size, void* d_ws, size_t ws_size,
                              hipStream_t stream) {
    (void)in_sizes; (void)n_in; (void)out_size;

    float* props = (float*)d_out;
    float* Mbuf  = props + (size_t)ROWS_ * PW_;

    char* ws = (char*)d_ws;
    int* flags = (int*)(ws + OFF_FLAGS);
    float* feat = (float*)(ws + OFF_FEAT);
    char* canon = ws + OFF_CANON;
    unsigned short* cx    = (unsigned short*)(canon + C_X);
    unsigned short* cattw = (unsigned short*)(canon + C_ATTW);
    unsigned short* ccw   = (unsigned short*)(canon + C_CW);
    unsigned short* canch = (unsigned short*)(canon + C_ANCH);
    unsigned short* cclsw = (unsigned short*)(canon + C_CLSW);
    unsigned short* cregw = (unsigned short*)(canon + C_REGW);
    unsigned short* ccb   = (unsigned short*)(canon + C_CB);
    unsigned short* cattb = (unsigned short*)(canon + C_ATTB);
    unsigned short* cclsb = (unsigned short*)(canon + C_CLSB);
    unsigned short* cregb = (unsigned short*)(canon + C_REGB);
    int* ccut = (int*)(canon + C_CUT);
    int* cmsk = (int*)(canon + C_MASK);

    const size_t base = (size_t)(12u << 20);
    const size_t per  = ((size_t)N_ * D_ * 2) * 2 + (size_t)D_ * PK_ * 2 + (size_t)N_ * PK_ * 2;
    int CN = 1;
    for (int c = 16; c >= 1; c >>= 1)
        if (ws_size >= base + (size_t)c * per) { CN = c; break; }
    unsigned short* AF  = (unsigned short*)(ws + base);
    unsigned short* AFT = AF  + (size_t)CN * N_ * D_;
    unsigned short* ATF = AFT + (size_t)CN * D_ * PK_;
    unsigned short* Mbf = ATF + (size_t)CN * N_ * D_;

    k_detect<<<dim3(1), dim3(256), 0, stream>>>((const unsigned int*)d_in[3],
                                                (const unsigned int*)d_in[10],
                                                (const unsigned int*)d_in[11], flags);
    k_canon_f<<<dim3(1024), dim3(256), 0, stream>>>(d_in[0], d_in[1], d_in[2], d_in[3], d_in[4],
                                                    d_in[5], d_in[6], d_in[7], d_in[8], d_in[9],
                                                    canon, flags);
    k_canon_i<<<dim3(120), dim3(256), 0, stream>>>(d_in[10], d_in[11], canon, flags);
    k_conv<<<dim3(880), dim3(256), 0, stream>>>(cx, ccw, ccb, feat);

    const int nchunk = 16 / CN;
    for (int c = 0; c < nchunk; ++c) {
        const int bb = c * CN;
        const int rb = bb * N_;
        const int nl = CN * N_;
        const int it128 = (nl + 127) / 128;
        const int it256 = (nl + 255) / 256;
        k_gather_af<<<dim3(N_, CN), dim3(256), 0, stream>>>(feat, ccut, cmsk, AF, bb);
        k_gather_aft<<<dim3(D_, CN), dim3(256), 0, stream>>>(feat, ccut, cmsk, AFT, bb);
        k_scores<<<dim3(11, it256), dim3(512), 0, stream>>>(AF, cattw, cattb, Mbf, nl);
        k_softmax<<<dim3(nl), dim3(256), 0, stream>>>(Mbf, Mbuf, rb);
        k_attgemm<<<dim3(3, 11, CN), dim3(512), 0, stream>>>(Mbf, AFT, ATF);
        k_head<<<dim3(it128), dim3(256), 0, stream>>>(ATF, AF, cclsw, cclsb, cregw, cregb,
                                                      canch, props, rb, nl);
    }
}

// Round 16
// 990.655 us; speedup vs baseline: 1.0057x; 1.0057x over previous
//
#include <hip/hip_runtime.h>

#define B_    16
#define CIN_  512
#define CF_   64
#define FH_   11
#define FW_   20
#define N_    2784
#define NM1_  2783
#define PK_   2816
#define D_    704
#define D2_   1408
#define ROWS_ 44544
#define PW_   77

// ---- input element counts
#define NX_     1802240
#define NCW_    32768
#define NCB_    64
#define NATTW_  1959232
#define NATTB_  2783
#define NCLSW_  2816
#define NCLSB_  2
#define NREGW_  102784
#define NREGB_  73
#define NANCH_  214368
#define NCUT_   30624

// ---- canonical ws layout (byte offsets)
#define OFF_FLAGS   0u
#define OFF_FEAT    256u
#define OFF_CANON   (1u<<20)
#define C_X      0u
#define C_ATTW   3604480u
#define C_CW     7522944u
#define C_ANCH   7588480u
#define C_CLSW   8017216u
#define C_REGW   8022848u
#define C_CB     8228416u
#define C_ATTB   8228544u
#define C_CLSB   8234112u
#define C_REGB   8234128u
#define C_CUT    8234288u
#define C_MASK   8356784u

typedef __bf16 bf16x8 __attribute__((ext_vector_type(8)));
typedef float  f32x4  __attribute__((ext_vector_type(4)));

typedef __attribute__((address_space(1))) void g_void;
typedef __attribute__((address_space(3))) void l_void;
#define GLD16(gp, lp) __builtin_amdgcn_global_load_lds((g_void*)(gp), (l_void*)(lp), 16, 0, 0)

// row permutation + chunk swizzle for 64B-row K-half LDS tiles
#define PHYS(R)  ((((R) & 1) << 7) | ((R) >> 1))
#define GLOB(P)  ((((P) & 127) << 1) | ((P) >> 7))
#define G2P(P)   (((P) + ((P) >> 1)) & 3)

__device__ __forceinline__ float bf2f(unsigned short u) {
    union { unsigned int u; float f; } v; v.u = ((unsigned int)u) << 16; return v.f;
}
__device__ __forceinline__ unsigned short f2bf(float f) {
    union { float f; unsigned int u; } v; v.f = f;
    unsigned int x = v.u;
    return (unsigned short)((x + 0x7FFFu + ((x >> 16) & 1u)) >> 16);
}

// m204 bijective XCD swizzle
__device__ __forceinline__ int swz8(int olid, int nwg) {
    int xcd = olid & 7, pos = olid >> 3;
    int q = nwg >> 3, r = nwg & 7;
    int off = (xcd < r) ? xcd * (q + 1) : r * (q + 1) + (xcd - r) * q;
    return off + pos;
}

// ---------------- K0: dtype detection
__global__ __launch_bounds__(256) void k_detect(const unsigned int* __restrict__ attw,
                                                const unsigned int* __restrict__ cut,
                                                const unsigned int* __restrict__ msk,
                                                int* __restrict__ flags) {
    __shared__ int cnt[3];
    int t = threadIdx.x;
    if (t < 3) cnt[t] = 0;
    __syncthreads();
    int c0 = 0, c1 = 0, c2 = 0;
    for (int i = t; i < 2048; i += 256) {
        unsigned int e = (attw[i] >> 7) & 0xFFu;
        if (e >= 127u) c0++;
    }
    for (int i = t; i < 4096; i += 256) if (cut[i] >= 32u) c1++;
    for (int i = t; i < 4096; i += 256) if (msk[i] >= 2u)  c2++;
    atomicAdd(&cnt[0], c0); atomicAdd(&cnt[1], c1); atomicAdd(&cnt[2], c2);
    __syncthreads();
    if (t == 0) {
        flags[0] = cnt[0] > 64;
        flags[1] = cnt[1] > 64;
        flags[2] = cnt[2] > 64;
        flags[3] = 0;
    }
}

// ---------------- K0b: canonicalize float inputs to bf16
__device__ __forceinline__ void cvt_arr(const void* s, unsigned short* d, int n, int isf32,
                                        int tid, int stride) {
    if (isf32) {
        const float* p = (const float*)s;
        for (int i = tid; i < n; i += stride) d[i] = f2bf(p[i]);
    } else {
        const unsigned short* p = (const unsigned short*)s;
        for (int i = tid; i < n; i += stride) d[i] = p[i];
    }
}

__global__ __launch_bounds__(256) void k_canon_f(const void* sx, const void* scw, const void* scb,
                                                 const void* sattw, const void* sattb,
                                                 const void* sclsw, const void* sclsb,
                                                 const void* sregw, const void* sregb,
                                                 const void* sanch, char* canon,
                                                 const int* __restrict__ flags) {
    const int isf32 = flags[0];
    const int tid = blockIdx.x * 256 + threadIdx.x;
    const int stride = gridDim.x * 256;
    cvt_arr(sx,    (unsigned short*)(canon + C_X),    NX_,    isf32, tid, stride);
    cvt_arr(sattw, (unsigned short*)(canon + C_ATTW), NATTW_, isf32, tid, stride);
    cvt_arr(scw,   (unsigned short*)(canon + C_CW),   NCW_,   isf32, tid, stride);
    cvt_arr(sanch, (unsigned short*)(canon + C_ANCH), NANCH_, isf32, tid, stride);
    cvt_arr(sclsw, (unsigned short*)(canon + C_CLSW), NCLSW_, isf32, tid, stride);
    cvt_arr(sregw, (unsigned short*)(canon + C_REGW), NREGW_, isf32, tid, stride);
    cvt_arr(scb,   (unsigned short*)(canon + C_CB),   NCB_,   isf32, tid, stride);
    cvt_arr(sattb, (unsigned short*)(canon + C_ATTB), NATTB_, isf32, tid, stride);
    cvt_arr(sclsb, (unsigned short*)(canon + C_CLSB), NCLSB_, isf32, tid, stride);
    cvt_arr(sregb, (unsigned short*)(canon + C_REGB), NREGB_, isf32, tid, stride);
}

// ---------------- K0c: canonicalize int inputs to int32
__global__ __launch_bounds__(256) void k_canon_i(const void* scut, const void* smsk,
                                                 char* canon, const int* __restrict__ flags) {
    const int cutb = flags[1], mskb = flags[2];
    int* ccut = (int*)(canon + C_CUT);
    int* cmsk = (int*)(canon + C_MASK);
    const int tid = blockIdx.x * 256 + threadIdx.x;
    const int stride = gridDim.x * 256;
    for (int i = tid; i < NCUT_; i += stride) {
        ccut[i] = cutb ? (int)((const unsigned char*)scut)[i] : ((const int*)scut)[i];
        int m = mskb ? (int)((const unsigned char*)smsk)[i] : ((const int*)smsk)[i];
        cmsk[i] = (m != 0);
    }
}

// ---------------- K1: 1x1 conv
__global__ __launch_bounds__(256) void k_conv(const unsigned short* __restrict__ x,
                                              const unsigned short* __restrict__ cw,
                                              const unsigned short* __restrict__ cb,
                                              float* __restrict__ feat) {
    int idx = blockIdx.x * 256 + threadIdx.x;
    int w = idx % FW_;
    int h = (idx / FW_) % FH_;
    int o = (idx / (FW_ * FH_)) % CF_;
    int b = idx / (FW_ * FH_ * CF_);
    const unsigned short* xp = x + ((size_t)(b * CIN_) * FH_ + h) * FW_ + w;
    const unsigned short* wp = cw + (size_t)o * CIN_;
    float acc = bf2f(cb[o]);
#pragma unroll 8
    for (int c = 0; c < CIN_; ++c)
        acc += bf2f(xp[(size_t)c * (FH_ * FW_)]) * bf2f(wp[c]);
    feat[idx] = acc;
}

// ---------------- K2a: AF chunk
__global__ __launch_bounds__(256) void k_gather_af(const float* __restrict__ feat,
                                                   const int* __restrict__ cut,
                                                   const int* __restrict__ inv,
                                                   unsigned short* __restrict__ AF,
                                                   int batch_base) {
    int n = blockIdx.x, bl = blockIdx.y;
    int b = batch_base + bl;
    __shared__ int cu[FH_];
    __shared__ int iv[FH_];
    int t = threadIdx.x;
    if (t < FH_) { cu[t] = cut[n * FH_ + t]; iv[t] = inv[n * FH_ + t]; }
    __syncthreads();
    unsigned short* out = AF + ((size_t)(bl * N_ + n)) * D_;
    for (int d = t; d < D_; d += 256) {
        int c = d / FH_, h = d - c * FH_;
        float v = iv[h] ? 0.f : feat[((b * CF_ + c) * FH_ + h) * FW_ + cu[h]];
        out[d] = f2bf(v);
    }
}

// ---------------- K2b: AFT chunk (stride PK_, pad cols zeroed)
__global__ __launch_bounds__(256) void k_gather_aft(const float* __restrict__ feat,
                                                    const int* __restrict__ cut,
                                                    const int* __restrict__ inv,
                                                    unsigned short* __restrict__ AFT,
                                                    int batch_base) {
    int d = blockIdx.x, bl = blockIdx.y;
    int b = batch_base + bl;
    int c = d / FH_, h = d - c * FH_;
    const float* fp = feat + ((b * CF_ + c) * FH_ + h) * FW_;
    unsigned short* out = AFT + ((size_t)(bl * D_ + d)) * PK_;
    for (int n = threadIdx.x; n < PK_; n += 256) {
        float v = 0.f;
        if (n < N_) {
            int w = cut[n * FH_ + h];
            v = inv[n * FH_ + h] ? 0.f : fp[w];
        }
        out[n] = f2bf(v);
    }
}

// ======== shared 8-phase GEMM body (192x256 tile, 512 thr, 8 waves 2x4, BK=64) ========
// LDS per matrix: [2 buf][2 khalf][256 phys-rows x 32 K] (A rows 192..255 are pad,
// staged-but-unused). Wave-tile 96x64, acc[6][4]. Staging identical to r14.

#define GEMM_PROLOGUE()                                                               \
    STAGE_A(0, 0, 0); STAGE_B(0, 0, 0); STAGE_A(0, 1, 0); STAGE_B(0, 1, 0);           \
    STAGE_A(1, 0, 1); STAGE_B(1, 0, 1);

#define RD_A(kh)                                                                      \
    _Pragma("unroll")                                                                 \
    for (int m = 0; m < 6; ++m)                                                       \
        a[m] = *(const bf16x8*)(As + cur * 16384 + (kh) * 8192 + aoff[m]);

#define RD_B(kh, n0)                                                                  \
    {                                                                                 \
        b0 = *(const bf16x8*)(Bs + cur * 16384 + (kh) * 8192 + boff[(n0)]);           \
        b1 = *(const bf16x8*)(Bs + cur * 16384 + (kh) * 8192 + boff[(n0) + 1]);       \
    }

#define MFMA12(n0)                                                                    \
    asm volatile("s_waitcnt lgkmcnt(0)" ::: "memory");                                \
    __builtin_amdgcn_sched_barrier(0);                                                \
    __builtin_amdgcn_s_setprio(1);                                                    \
    _Pragma("unroll")                                                                 \
    for (int m = 0; m < 6; ++m) {                                                     \
        acc[m][(n0)] = __builtin_amdgcn_mfma_f32_16x16x32_bf16(a[m], b0, acc[m][(n0)], 0, 0, 0); \
        acc[m][(n0) + 1] = __builtin_amdgcn_mfma_f32_16x16x32_bf16(a[m], b1, acc[m][(n0) + 1], 0, 0, 0); \
    }                                                                                 \
    __builtin_amdgcn_s_setprio(0);

#define BOUNDARY(tail)                                                                \
    if (tail) asm volatile("s_waitcnt vmcnt(0)" ::: "memory");                        \
    else      asm volatile("s_waitcnt vmcnt(8)" ::: "memory");                        \
    __builtin_amdgcn_sched_barrier(0);                                                \
    __builtin_amdgcn_s_barrier();

#define GEMM_LOOP(NT)                                                                 \
    for (int tt = 0; tt < (NT); ++tt) {                                               \
        const int cur = tt & 1, nxt = cur ^ 1;                                        \
        const bool tail = (tt >= (NT) - 2);                                           \
        BOUNDARY(tail);                                                               \
        RD_A(0); RD_B(0, 0);                                                          \
        if (tt + 1 < (NT)) STAGE_A(nxt, 1, tt + 1);                                   \
        MFMA12(0);                                                                    \
        __builtin_amdgcn_s_barrier();                                                 \
        RD_B(0, 2);                                                                   \
        if (tt + 1 < (NT)) STAGE_B(nxt, 1, tt + 1);                                   \
        MFMA12(2);                                                                    \
        __builtin_amdgcn_s_barrier();                                                 \
        BOUNDARY(tail);                                                               \
        RD_A(1); RD_B(1, 0);                                                          \
        if (tt + 2 < (NT)) STAGE_A(cur, 0, tt + 2);                                   \
        MFMA12(0);                                                                    \
        __builtin_amdgcn_s_barrier();                                                 \
        RD_B(1, 2);                                                                   \
        if (tt + 2 < (NT)) STAGE_B(cur, 0, tt + 2);                                   \
        MFMA12(2);                                                                    \
    }

#define MK_OFFS()                                                                     \
    int aoff[6], boff[4];                                                             \
    _Pragma("unroll")                                                                 \
    for (int m = 0; m < 6; ++m) {                                                     \
        int R = wrow * 96 + m * 16 + l15;                                             \
        int P = PHYS(R);                                                              \
        aoff[m] = P * 32 + ((hi ^ G2P(P)) * 8);                                       \
    }                                                                                 \
    _Pragma("unroll")                                                                 \
    for (int n = 0; n < 4; ++n) {                                                     \
        int R = wcol * 64 + n * 16 + l15;                                             \
        int P = PHYS(R);                                                              \
        boff[n] = P * 32 + ((hi ^ G2P(P)) * 8);                                       \
    }

// ---------------- K3a: MFMA scores GEMM (8-phase, M=192 tiles)
__global__ __launch_bounds__(512, 1) void k_scores(const unsigned short* __restrict__ AF,
                                                   const unsigned short* __restrict__ attw,
                                                   const unsigned short* __restrict__ attb,
                                                   unsigned short* __restrict__ Mbf,
                                                   int nloc) {
    __shared__ __bf16 As[2 * 16384];
    __shared__ __bf16 Bs[2 * 16384];
    const int t = threadIdx.x;
    const int nwg = gridDim.x * gridDim.y;
    const int olid = blockIdx.x + gridDim.x * blockIdx.y;
    const int nid = swz8(olid, nwg);
    const int jt = nid % 11, it = nid / 11;
    const int i0 = it * 192, j0 = jt * 256;
    const int lane = t & 63, wv = t >> 6;
    const int wrow = wv >> 2, wcol = wv & 3;
    const int l15 = lane & 15, hi = lane >> 4;

    f32x4 zero = {0.f, 0.f, 0.f, 0.f};
    f32x4 acc[6][4];
#pragma unroll
    for (int m = 0; m < 6; ++m)
#pragma unroll
        for (int n = 0; n < 4; ++n) acc[m][n] = zero;

    MK_OFFS();

    const unsigned short *aB0, *aB1, *bB0, *bB1;
    {
        int P0 = t >> 2, P1 = (t + 512) >> 2;
        int g0 = GLOB(P0), g1 = GLOB(P1);
        int lc0 = (t & 3) ^ G2P(P0), lc1 = (t & 3) ^ G2P(P1);
        int ia0 = i0 + g0; if (ia0 > nloc - 1) ia0 = nloc - 1;
        int ia1 = i0 + g1; if (ia1 > nloc - 1) ia1 = nloc - 1;
        int jb0 = j0 + g0; if (jb0 > NM1_ - 1) jb0 = NM1_ - 1;
        int jb1 = j0 + g1; if (jb1 > NM1_ - 1) jb1 = NM1_ - 1;
        aB0 = AF + (size_t)ia0 * D_ + lc0 * 8;
        aB1 = AF + (size_t)ia1 * D_ + lc1 * 8;
        bB0 = attw + (size_t)jb0 * D_ + lc0 * 8;
        bB1 = attw + (size_t)jb1 * D_ + lc1 * 8;
    }
#define STAGE_A(buf, kh, kt) { \
    GLD16(aB0 + (kt) * 64 + (kh) * 32, As + (buf) * 16384 + (kh) * 8192 + t * 8); \
    GLD16(aB1 + (kt) * 64 + (kh) * 32, As + (buf) * 16384 + (kh) * 8192 + (t + 512) * 8); }
#define STAGE_B(buf, kh, kt) { \
    GLD16(bB0 + (kt) * 64 + (kh) * 32, Bs + (buf) * 16384 + (kh) * 8192 + t * 8); \
    GLD16(bB1 + (kt) * 64 + (kh) * 32, Bs + (buf) * 16384 + (kh) * 8192 + (t + 512) * 8); }

    bf16x8 a[6], b0, b1;
    GEMM_PROLOGUE();
    GEMM_LOOP(11);            // D_/64
#undef STAGE_A
#undef STAGE_B

#pragma unroll
    for (int m = 0; m < 6; ++m) {
        int ib = i0 + wrow * 96 + m * 16 + hi * 4;
#pragma unroll
        for (int n = 0; n < 4; ++n) {
            int j = j0 + wcol * 64 + n * 16 + l15;
            if (j < NM1_) {
                float bias = bf2f(attb[j]);
#pragma unroll
                for (int q = 0; q < 4; ++q) {
                    int ii = ib + q;
                    if (ii < nloc) {
                        int r = ii % N_;
                        int c = j + (j >= r);
                        Mbf[(size_t)ii * PK_ + c] = f2bf(acc[m][n][q] + bias);
                    }
                }
            }
        }
    }
}

// ---------------- K3b: bf16 row softmax IN PLACE (stride PK_, zero pad) + f32 M to d_out
__global__ __launch_bounds__(256) void k_softmax(unsigned short* __restrict__ Mbf,
                                                 float* __restrict__ Mout,
                                                 int row_base) {
    const int il = blockIdx.x;
    const int r = il % N_;
    unsigned short* srow = Mbf + (size_t)il * PK_;
    float* orow = Mout + (size_t)(row_base + il) * N_;
    const int t = threadIdx.x;
    float f[16];
#pragma unroll
    for (int q = 0; q < 2; ++q) {
        int c8 = t + 256 * q;
        if (c8 < N_ / 8) {
            uint4 u = *(const uint4*)(srow + c8 * 8);
            const unsigned short* pu = (const unsigned short*)&u;
#pragma unroll
            for (int e = 0; e < 8; ++e) {
                int c = c8 * 8 + e;
                float v = bf2f(pu[e]);
                f[q * 8 + e] = (c == r) ? -1e30f : v;
            }
        } else {
#pragma unroll
            for (int e = 0; e < 8; ++e) f[q * 8 + e] = -1e30f;
        }
    }
    float m = -1e30f;
#pragma unroll
    for (int q = 0; q < 16; ++q) m = fmaxf(m, f[q]);
#pragma unroll
    for (int off = 32; off >= 1; off >>= 1) m = fmaxf(m, __shfl_xor(m, off, 64));
    __shared__ float red[4];
    if ((t & 63) == 0) red[t >> 6] = m;
    __syncthreads();
    m = fmaxf(fmaxf(red[0], red[1]), fmaxf(red[2], red[3]));

    float s = 0.f;
#pragma unroll
    for (int q = 0; q < 16; ++q) { float e = __expf(f[q] - m); f[q] = e; s += e; }
#pragma unroll
    for (int off = 32; off >= 1; off >>= 1) s += __shfl_xor(s, off, 64);
    __shared__ float red2[4];
    if ((t & 63) == 0) red2[t >> 6] = s;
    __syncthreads();
    s = red2[0] + red2[1] + red2[2] + red2[3];
    float inv = 1.0f / s;
#pragma unroll
    for (int q = 0; q < 2; ++q) {
        int c8 = t + 256 * q;
        if (c8 < N_ / 8) {
            float o[8];
            union { unsigned short u[8]; uint4 v; } pb;
#pragma unroll
            for (int e = 0; e < 8; ++e) {
                o[e] = f[q * 8 + e] * inv;     // diag: exp(-1e30-m)=0 -> exact 0
                pb.u[e] = f2bf(o[e]);
            }
            float4 o0 = {o[0], o[1], o[2], o[3]};
            float4 o1 = {o[4], o[5], o[6], o[7]};
            *(float4*)(orow + c8 * 8) = o0;
            *(float4*)(orow + c8 * 8 + 4) = o1;
            *(uint4*)(srow + c8 * 8) = pb.v;
        }
    }
    if (t < 4) {
        uint4 z = {0u, 0u, 0u, 0u};
        *(uint4*)(srow + N_ + t * 8) = z;
    }
}

// ---------------- K4: MFMA att_feat = Mbf @ AF (8-phase, M=192 tiles)
__global__ __launch_bounds__(512, 1) void k_attgemm(const unsigned short* __restrict__ Mbf,
                                                    const unsigned short* __restrict__ AFT,
                                                    unsigned short* __restrict__ ATF) {
    __shared__ __bf16 As[2 * 16384];
    __shared__ __bf16 Bs[2 * 16384];
    const int t = threadIdx.x;
    const int nwg = gridDim.x * gridDim.y * gridDim.z;
    const int olid = blockIdx.x + gridDim.x * (blockIdx.y + gridDim.y * blockIdx.z);
    const int nid = swz8(olid, nwg);
    const int jt = nid % 3, it = (nid / 3) % 15, bl = nid / 45;
    const int i0 = it * 192, j0 = jt * 256;
    const int lane = t & 63, wv = t >> 6;
    const int wrow = wv >> 2, wcol = wv & 3;
    const int l15 = lane & 15, hi = lane >> 4;

    f32x4 zero = {0.f, 0.f, 0.f, 0.f};
    f32x4 acc[6][4];
#pragma unroll
    for (int m = 0; m < 6; ++m)
#pragma unroll
        for (int n = 0; n < 4; ++n) acc[m][n] = zero;

    MK_OFFS();

    const unsigned short *aB0, *aB1, *bB0, *bB1;
    {
        int P0 = t >> 2, P1 = (t + 512) >> 2;
        int g0 = GLOB(P0), g1 = GLOB(P1);
        int lc0 = (t & 3) ^ G2P(P0), lc1 = (t & 3) ^ G2P(P1);
        int ia0 = i0 + g0; if (ia0 > N_ - 1) ia0 = N_ - 1;
        int ia1 = i0 + g1; if (ia1 > N_ - 1) ia1 = N_ - 1;
        int jb0 = j0 + g0; if (jb0 > D_ - 1) jb0 = D_ - 1;
        int jb1 = j0 + g1; if (jb1 > D_ - 1) jb1 = D_ - 1;
        aB0 = Mbf + ((size_t)bl * N_ + ia0) * PK_ + lc0 * 8;
        aB1 = Mbf + ((size_t)bl * N_ + ia1) * PK_ + lc1 * 8;
        bB0 = AFT + ((size_t)bl * D_ + jb0) * PK_ + lc0 * 8;
        bB1 = AFT + ((size_t)bl * D_ + jb1) * PK_ + lc1 * 8;
    }
#define STAGE_A(buf, kh, kt) { \
    GLD16(aB0 + (kt) * 64 + (kh) * 32, As + (buf) * 16384 + (kh) * 8192 + t * 8); \
    GLD16(aB1 + (kt) * 64 + (kh) * 32, As + (buf) * 16384 + (kh) * 8192 + (t + 512) * 8); }
#define STAGE_B(buf, kh, kt) { \
    GLD16(bB0 + (kt) * 64 + (kh) * 32, Bs + (buf) * 16384 + (kh) * 8192 + t * 8); \
    GLD16(bB1 + (kt) * 64 + (kh) * 32, Bs + (buf) * 16384 + (kh) * 8192 + (t + 512) * 8); }

    bf16x8 a[6], b0, b1;
    GEMM_PROLOGUE();
    GEMM_LOOP(44);            // PK_/64
#undef STAGE_A
#undef STAGE_B

#pragma unroll
    for (int m = 0; m < 6; ++m) {
        int rb = i0 + wrow * 96 + m * 16 + hi * 4;
#pragma unroll
        for (int n = 0; n < 4; ++n) {
            int d = j0 + wcol * 64 + n * 16 + l15;
            if (d < D_) {
#pragma unroll
                for (int q = 0; q < 4; ++q) {
                    int rr = rb + q;
                    if (rr < N_)
                        ATF[((size_t)(bl * N_ + rr)) * D_ + d] = f2bf(acc[m][n][q]);
                }
            }
        }
    }
}

// ---------------- K5: MFMA heads + fused props epilogue (f32 out)
__global__ __launch_bounds__(256) void k_head(const unsigned short* __restrict__ ATF,
                                              const unsigned short* __restrict__ AF,
                                              const unsigned short* __restrict__ clsw,
                                              const unsigned short* __restrict__ clsb,
                                              const unsigned short* __restrict__ regw,
                                              const unsigned short* __restrict__ regb,
                                              const unsigned short* __restrict__ anch,
                                              float* __restrict__ props,
                                              int row_base, int nloc) {
    __shared__ __bf16 As2[128 * 32];
    __shared__ __bf16 Ws[80 * 32];
    const int t = threadIdx.x;
    const int i0 = blockIdx.x * 128;
    const int lane = t & 63, wv = t >> 6;
    const int l15 = lane & 15, hi8 = (lane >> 4) * 8;

    f32x4 zero = {0.f, 0.f, 0.f, 0.f};
    f32x4 acc[2][5];
#pragma unroll
    for (int m = 0; m < 2; ++m)
#pragma unroll
        for (int n = 0; n < 5; ++n) acc[m][n] = zero;

    const int s0 = t, s1 = t + 256;
    const int ar0 = s0 >> 2, ac0 = (s0 & 3) * 8;
    const int ar1 = s1 >> 2, ac1 = (s1 & 3) * 8;
    int ir0 = i0 + ar0; if (ir0 > nloc - 1) ir0 = nloc - 1;
    int ir1 = i0 + ar1; if (ir1 > nloc - 1) ir1 = nloc - 1;
    const unsigned short* w0base = (ar0 < 2) ? (clsw + (size_t)ar0 * D2_)
                                             : (regw + (size_t)(ar0 - 2) * D2_);
    int r1 = 64 + (t >> 2);
    int rc = r1 < 75 ? r1 : 74;
    const unsigned short* w1base = regw + (size_t)(rc - 2) * D2_;
    const int w1c = (t & 3) * 8;

    for (int p = 0; p < 2; ++p) {
        const unsigned short* Asrc = (p == 0) ? ATF : AF;
        const int wcol = p * D_;
        for (int k0 = 0; k0 < D_; k0 += 32) {
            GLD16(Asrc + (size_t)ir0 * D_ + ac0 + k0, As2 + s0 * 8);
            GLD16(Asrc + (size_t)ir1 * D_ + ac1 + k0, As2 + s1 * 8);
            GLD16(w0base + wcol + k0 + ac0, Ws + s0 * 8);
            if (t < 64) GLD16(w1base + wcol + k0 + w1c, Ws + (size_t)(256 + t) * 8);
            __syncthreads();
            bf16x8 a[2], bb[5];
#pragma unroll
            for (int m = 0; m < 2; ++m)
                a[m] = *(const bf16x8*)(As2 + (wv * 32 + m * 16 + l15) * 32 + hi8);
#pragma unroll
            for (int n = 0; n < 5; ++n)
                bb[n] = *(const bf16x8*)(Ws + (n * 16 + l15) * 32 + hi8);
#pragma unroll
            for (int m = 0; m < 2; ++m)
#pragma unroll
                for (int n = 0; n < 5; ++n)
                    acc[m][n] = __builtin_amdgcn_mfma_f32_16x16x32_bf16(a[m], bb[n], acc[m][n], 0, 0, 0);
            __syncthreads();
        }
    }

#pragma unroll
    for (int m = 0; m < 2; ++m) {
        int ib = i0 + wv * 32 + m * 16 + (lane >> 4) * 4;
#pragma unroll
        for (int n = 0; n < 5; ++n) {
            int j = n * 16 + l15;
            if (j < 75) {
#pragma unroll
                for (int q = 0; q < 4; ++q) {
                    int i = ib + q;
                    if (i < nloc) {
                        size_t g = (size_t)(row_base + i);
                        int nn = i % N_;
                        float v = acc[m][n][q];
                        if (j < 2) {
                            props[g * PW_ + j] = v + bf2f(clsb[j]);
                            props[g * PW_ + 2 + j] = bf2f(anch[(size_t)nn * PW_ + 2 + j]);
                        } else {
                            int tt = j - 2;
                            props[g * PW_ + 4 + tt] = v + bf2f(regb[tt]) + bf2f(anch[(size_t)nn * PW_ + 4 + tt]);
                        }
                    }
                }
            }
        }
    }
}

extern "C" void kernel_launch(void* const* d_in, const int* in_sizes, int n_in,
                              void* d_out, int out_size, void* d_ws, size_t ws_size,
                              hipStream_t stream) {
    (void)in_sizes; (void)n_in; (void)out_size;

    float* props = (float*)d_out;
    float* Mbuf  = props + (size_t)ROWS_ * PW_;

    char* ws = (char*)d_ws;
    int* flags = (int*)(ws + OFF_FLAGS);
    float* feat = (float*)(ws + OFF_FEAT);
    char* canon = ws + OFF_CANON;
    unsigned short* cx    = (unsigned short*)(canon + C_X);
    unsigned short* cattw = (unsigned short*)(canon + C_ATTW);
    unsigned short* ccw   = (unsigned short*)(canon + C_CW);
    unsigned short* canch = (unsigned short*)(canon + C_ANCH);
    unsigned short* cclsw = (unsigned short*)(canon + C_CLSW);
    unsigned short* cregw = (unsigned short*)(canon + C_REGW);
    unsigned short* ccb   = (unsigned short*)(canon + C_CB);
    unsigned short* cattb = (unsigned short*)(canon + C_ATTB);
    unsigned short* cclsb = (unsigned short*)(canon + C_CLSB);
    unsigned short* cregb = (unsigned short*)(canon + C_REGB);
    int* ccut = (int*)(canon + C_CUT);
    int* cmsk = (int*)(canon + C_MASK);

    const size_t base = (size_t)(12u << 20);
    const size_t per  = ((size_t)N_ * D_ * 2) * 2 + (size_t)D_ * PK_ * 2 + (size_t)N_ * PK_ * 2;
    int CN = 1;
    for (int c = 16; c >= 1; c >>= 1)
        if (ws_size >= base + (size_t)c * per) { CN = c; break; }
    unsigned short* AF  = (unsigned short*)(ws + base);
    unsigned short* AFT = AF  + (size_t)CN * N_ * D_;
    unsigned short* ATF = AFT + (size_t)CN * D_ * PK_;
    unsigned short* Mbf = ATF + (size_t)CN * N_ * D_;

    k_detect<<<dim3(1), dim3(256), 0, stream>>>((const unsigned int*)d_in[3],
                                                (const unsigned int*)d_in[10],
                                                (const unsigned int*)d_in[11], flags);
    k_canon_f<<<dim3(1024), dim3(256), 0, stream>>>(d_in[0], d_in[1], d_in[2], d_in[3], d_in[4],
                                                    d_in[5], d_in[6], d_in[7], d_in[8], d_in[9],
                                                    canon, flags);
    k_canon_i<<<dim3(120), dim3(256), 0, stream>>>(d_in[10], d_in[11], canon, flags);
    k_conv<<<dim3(880), dim3(256), 0, stream>>>(cx, ccw, ccb, feat);

    const int nchunk = 16 / CN;
    for (int c = 0; c < nchunk; ++c) {
        const int bb = c * CN;
        const int rb = bb * N_;
        const int nl = CN * N_;
        const int it128 = (nl + 127) / 128;
        const int it192 = (nl + 191) / 192;
        const int at192 = (N_ + 191) / 192;   // 15
        k_gather_af<<<dim3(N_, CN), dim3(256), 0, stream>>>(feat, ccut, cmsk, AF, bb);
        k_gather_aft<<<dim3(D_, CN), dim3(256), 0, stream>>>(feat, ccut, cmsk, AFT, bb);
        k_scores<<<dim3(11, it192), dim3(512), 0, stream>>>(AF, cattw, cattb, Mbf, nl);
        k_softmax<<<dim3(nl), dim3(256), 0, stream>>>(Mbf, Mbuf, rb);
        k_attgemm<<<dim3(3, at192, CN), dim3(512), 0, stream>>>(Mbf, AFT, ATF);
        k_head<<<dim3(it128), dim3(256), 0, stream>>>(ATF, AF, cclsw, cclsb, cregw, cregb,
                                                      canch, props, rb, nl);
    }
}

// Round 17
// 978.680 us; speedup vs baseline: 1.0180x; 1.0122x over previous
//
#include <hip/hip_runtime.h>

#define B_    16
#define CIN_  512
#define CF_   64
#define FH_   11
#define FW_   20
#define N_    2784
#define NM1_  2783
#define PK_   2816
#define D_    704
#define D2_   1408
#define ROWS_ 44544
#define PW_   77

// ---- input element counts
#define NX_     1802240
#define NCW_    32768
#define NCB_    64
#define NATTW_  1959232
#define NATTB_  2783
#define NCLSW_  2816
#define NCLSB_  2
#define NREGW_  102784
#define NREGB_  73
#define NANCH_  214368
#define NCUT_   30624

// ---- canonical ws layout (byte offsets)
#define OFF_FLAGS   0u
#define OFF_FEAT    256u
#define OFF_CANON   (1u<<20)
#define C_X      0u
#define C_ATTW   3604480u
#define C_CW     7522944u
#define C_ANCH   7588480u
#define C_CLSW   8017216u
#define C_REGW   8022848u
#define C_CB     8228416u
#define C_ATTB   8228544u
#define C_CLSB   8234112u
#define C_REGB   8234128u
#define C_CUT    8234288u
#define C_MASK   8356784u

typedef __bf16 bf16x8 __attribute__((ext_vector_type(8)));
typedef float  f32x4  __attribute__((ext_vector_type(4)));

typedef __attribute__((address_space(1))) void g_void;
typedef __attribute__((address_space(3))) void l_void;
#define GLD16(gp, lp) __builtin_amdgcn_global_load_lds((g_void*)(gp), (l_void*)(lp), 16, 0, 0)

// row permutation + chunk swizzle for 64B-row K-half LDS tiles
#define PHYS(R)  ((((R) & 1) << 7) | ((R) >> 1))
#define GLOB(P)  ((((P) & 127) << 1) | ((P) >> 7))
#define G2P(P)   (((P) + ((P) >> 1)) & 3)

__device__ __forceinline__ float bf2f(unsigned short u) {
    union { unsigned int u; float f; } v; v.u = ((unsigned int)u) << 16; return v.f;
}
__device__ __forceinline__ unsigned short f2bf(float f) {
    union { float f; unsigned int u; } v; v.f = f;
    unsigned int x = v.u;
    return (unsigned short)((x + 0x7FFFu + ((x >> 16) & 1u)) >> 16);
}

// m204 bijective XCD swizzle
__device__ __forceinline__ int swz8(int olid, int nwg) {
    int xcd = olid & 7, pos = olid >> 3;
    int q = nwg >> 3, r = nwg & 7;
    int off = (xcd < r) ? xcd * (q + 1) : r * (q + 1) + (xcd - r) * q;
    return off + pos;
}

// ---------------- K0: dtype detection
__global__ __launch_bounds__(256) void k_detect(const unsigned int* __restrict__ attw,
                                                const unsigned int* __restrict__ cut,
                                                const unsigned int* __restrict__ msk,
                                                int* __restrict__ flags) {
    __shared__ int cnt[3];
    int t = threadIdx.x;
    if (t < 3) cnt[t] = 0;
    __syncthreads();
    int c0 = 0, c1 = 0, c2 = 0;
    for (int i = t; i < 2048; i += 256) {
        unsigned int e = (attw[i] >> 7) & 0xFFu;
        if (e >= 127u) c0++;
    }
    for (int i = t; i < 4096; i += 256) if (cut[i] >= 32u) c1++;
    for (int i = t; i < 4096; i += 256) if (msk[i] >= 2u)  c2++;
    atomicAdd(&cnt[0], c0); atomicAdd(&cnt[1], c1); atomicAdd(&cnt[2], c2);
    __syncthreads();
    if (t == 0) {
        flags[0] = cnt[0] > 64;
        flags[1] = cnt[1] > 64;
        flags[2] = cnt[2] > 64;
        flags[3] = 0;
    }
}

// ---------------- K0b: canonicalize float inputs to bf16
__device__ __forceinline__ void cvt_arr(const void* s, unsigned short* d, int n, int isf32,
                                        int tid, int stride) {
    if (isf32) {
        const float* p = (const float*)s;
        for (int i = tid; i < n; i += stride) d[i] = f2bf(p[i]);
    } else {
        const unsigned short* p = (const unsigned short*)s;
        for (int i = tid; i < n; i += stride) d[i] = p[i];
    }
}

__global__ __launch_bounds__(256) void k_canon_f(const void* sx, const void* scw, const void* scb,
                                                 const void* sattw, const void* sattb,
                                                 const void* sclsw, const void* sclsb,
                                                 const void* sregw, const void* sregb,
                                                 const void* sanch, char* canon,
                                                 const int* __restrict__ flags) {
    const int isf32 = flags[0];
    const int tid = blockIdx.x * 256 + threadIdx.x;
    const int stride = gridDim.x * 256;
    cvt_arr(sx,    (unsigned short*)(canon + C_X),    NX_,    isf32, tid, stride);
    cvt_arr(sattw, (unsigned short*)(canon + C_ATTW), NATTW_, isf32, tid, stride);
    cvt_arr(scw,   (unsigned short*)(canon + C_CW),   NCW_,   isf32, tid, stride);
    cvt_arr(sanch, (unsigned short*)(canon + C_ANCH), NANCH_, isf32, tid, stride);
    cvt_arr(sclsw, (unsigned short*)(canon + C_CLSW), NCLSW_, isf32, tid, stride);
    cvt_arr(sregw, (unsigned short*)(canon + C_REGW), NREGW_, isf32, tid, stride);
    cvt_arr(scb,   (unsigned short*)(canon + C_CB),   NCB_,   isf32, tid, stride);
    cvt_arr(sattb, (unsigned short*)(canon + C_ATTB), NATTB_, isf32, tid, stride);
    cvt_arr(sclsb, (unsigned short*)(canon + C_CLSB), NCLSB_, isf32, tid, stride);
    cvt_arr(sregb, (unsigned short*)(canon + C_REGB), NREGB_, isf32, tid, stride);
}

// ---------------- K0c: canonicalize int inputs to int32
__global__ __launch_bounds__(256) void k_canon_i(const void* scut, const void* smsk,
                                                 char* canon, const int* __restrict__ flags) {
    const int cutb = flags[1], mskb = flags[2];
    int* ccut = (int*)(canon + C_CUT);
    int* cmsk = (int*)(canon + C_MASK);
    const int tid = blockIdx.x * 256 + threadIdx.x;
    const int stride = gridDim.x * 256;
    for (int i = tid; i < NCUT_; i += stride) {
        ccut[i] = cutb ? (int)((const unsigned char*)scut)[i] : ((const int*)scut)[i];
        int m = mskb ? (int)((const unsigned char*)smsk)[i] : ((const int*)smsk)[i];
        cmsk[i] = (m != 0);
    }
}

// ---------------- K1: 1x1 conv
__global__ __launch_bounds__(256) void k_conv(const unsigned short* __restrict__ x,
                                              const unsigned short* __restrict__ cw,
                                              const unsigned short* __restrict__ cb,
                                              float* __restrict__ feat) {
    int idx = blockIdx.x * 256 + threadIdx.x;
    int w = idx % FW_;
    int h = (idx / FW_) % FH_;
    int o = (idx / (FW_ * FH_)) % CF_;
    int b = idx / (FW_ * FH_ * CF_);
    const unsigned short* xp = x + ((size_t)(b * CIN_) * FH_ + h) * FW_ + w;
    const unsigned short* wp = cw + (size_t)o * CIN_;
    float acc = bf2f(cb[o]);
#pragma unroll 8
    for (int c = 0; c < CIN_; ++c)
        acc += bf2f(xp[(size_t)c * (FH_ * FW_)]) * bf2f(wp[c]);
    feat[idx] = acc;
}

// ---------------- K2a: AF chunk
__global__ __launch_bounds__(256) void k_gather_af(const float* __restrict__ feat,
                                                   const int* __restrict__ cut,
                                                   const int* __restrict__ inv,
                                                   unsigned short* __restrict__ AF,
                                                   int batch_base) {
    int n = blockIdx.x, bl = blockIdx.y;
    int b = batch_base + bl;
    __shared__ int cu[FH_];
    __shared__ int iv[FH_];
    int t = threadIdx.x;
    if (t < FH_) { cu[t] = cut[n * FH_ + t]; iv[t] = inv[n * FH_ + t]; }
    __syncthreads();
    unsigned short* out = AF + ((size_t)(bl * N_ + n)) * D_;
    for (int d = t; d < D_; d += 256) {
        int c = d / FH_, h = d - c * FH_;
        float v = iv[h] ? 0.f : feat[((b * CF_ + c) * FH_ + h) * FW_ + cu[h]];
        out[d] = f2bf(v);
    }
}

// ---------------- K2b: AFT chunk (stride PK_, pad cols zeroed)
__global__ __launch_bounds__(256) void k_gather_aft(const float* __restrict__ feat,
                                                    const int* __restrict__ cut,
                                                    const int* __restrict__ inv,
                                                    unsigned short* __restrict__ AFT,
                                                    int batch_base) {
    int d = blockIdx.x, bl = blockIdx.y;
    int b = batch_base + bl;
    int c = d / FH_, h = d - c * FH_;
    const float* fp = feat + ((b * CF_ + c) * FH_ + h) * FW_;
    unsigned short* out = AFT + ((size_t)(bl * D_ + d)) * PK_;
    for (int n = threadIdx.x; n < PK_; n += 256) {
        float v = 0.f;
        if (n < N_) {
            int w = cut[n * FH_ + h];
            v = inv[n * FH_ + h] ? 0.f : fp[w];
        }
        out[n] = f2bf(v);
    }
}

// ======== shared 8-phase GEMM body (512 thr, 8 waves 2x4, BK=64) ========
// MC = A-frags/wave (8 -> M=256, span 128; 6 -> M=192, span 96).
// LDS per matrix: [2 buf][2 khalf][256 phys-rows x 32 K].

#define GEMM_PROLOGUE()                                                               \
    STAGE_A(0, 0, 0); STAGE_B(0, 0, 0); STAGE_A(0, 1, 0); STAGE_B(0, 1, 0);           \
    STAGE_A(1, 0, 1); STAGE_B(1, 0, 1);

#define RD_A(kh, MC)                                                                  \
    _Pragma("unroll")                                                                 \
    for (int m = 0; m < (MC); ++m)                                                    \
        a[m] = *(const bf16x8*)(As + cur * 16384 + (kh) * 8192 + aoff[m]);

#define RD_B(kh, n0)                                                                  \
    {                                                                                 \
        b0 = *(const bf16x8*)(Bs + cur * 16384 + (kh) * 8192 + boff[(n0)]);           \
        b1 = *(const bf16x8*)(Bs + cur * 16384 + (kh) * 8192 + boff[(n0) + 1]);       \
    }

#define MFMAX(n0, MC)                                                                 \
    asm volatile("s_waitcnt lgkmcnt(0)" ::: "memory");                                \
    __builtin_amdgcn_sched_barrier(0);                                                \
    __builtin_amdgcn_s_setprio(1);                                                    \
    _Pragma("unroll")                                                                 \
    for (int m = 0; m < (MC); ++m) {                                                  \
        acc[m][(n0)] = __builtin_amdgcn_mfma_f32_16x16x32_bf16(a[m], b0, acc[m][(n0)], 0, 0, 0); \
        acc[m][(n0) + 1] = __builtin_amdgcn_mfma_f32_16x16x32_bf16(a[m], b1, acc[m][(n0) + 1], 0, 0, 0); \
    }                                                                                 \
    __builtin_amdgcn_s_setprio(0);

#define BOUNDARY(tail)                                                                \
    if (tail) asm volatile("s_waitcnt vmcnt(0)" ::: "memory");                        \
    else      asm volatile("s_waitcnt vmcnt(8)" ::: "memory");                        \
    __builtin_amdgcn_sched_barrier(0);                                                \
    __builtin_amdgcn_s_barrier();

#define GEMM_LOOP(NT, MC)                                                             \
    for (int tt = 0; tt < (NT); ++tt) {                                               \
        const int cur = tt & 1, nxt = cur ^ 1;                                        \
        const bool tail = (tt >= (NT) - 2);                                           \
        BOUNDARY(tail);                                                               \
        RD_A(0, MC); RD_B(0, 0);                                                      \
        if (tt + 1 < (NT)) STAGE_A(nxt, 1, tt + 1);                                   \
        MFMAX(0, MC);                                                                 \
        __builtin_amdgcn_s_barrier();                                                 \
        RD_B(0, 2);                                                                   \
        if (tt + 1 < (NT)) STAGE_B(nxt, 1, tt + 1);                                   \
        MFMAX(2, MC);                                                                 \
        __builtin_amdgcn_s_barrier();                                                 \
        BOUNDARY(tail);                                                               \
        RD_A(1, MC); RD_B(1, 0);                                                      \
        if (tt + 2 < (NT)) STAGE_A(cur, 0, tt + 2);                                   \
        MFMAX(0, MC);                                                                 \
        __builtin_amdgcn_s_barrier();                                                 \
        RD_B(1, 2);                                                                   \
        if (tt + 2 < (NT)) STAGE_B(cur, 0, tt + 2);                                   \
        MFMAX(2, MC);                                                                 \
    }

#define MK_OFFS(MC, SPAN)                                                             \
    int aoff[MC], boff[4];                                                            \
    _Pragma("unroll")                                                                 \
    for (int m = 0; m < (MC); ++m) {                                                  \
        int R = wrow * (SPAN) + m * 16 + l15;                                         \
        int P = PHYS(R);                                                              \
        aoff[m] = P * 32 + ((hi ^ G2P(P)) * 8);                                       \
    }                                                                                 \
    _Pragma("unroll")                                                                 \
    for (int n = 0; n < 4; ++n) {                                                     \
        int R = wcol * 64 + n * 16 + l15;                                             \
        int P = PHYS(R);                                                              \
        boff[n] = P * 32 + ((hi ^ G2P(P)) * 8);                                       \
    }

// ---------------- K3a: MFMA scores GEMM (8-phase, M=256 tiles, hoisted modulo)
__global__ __launch_bounds__(512, 1) void k_scores(const unsigned short* __restrict__ AF,
                                                   const unsigned short* __restrict__ attw,
                                                   const unsigned short* __restrict__ attb,
                                                   unsigned short* __restrict__ Mbf,
                                                   int nloc) {
    __shared__ __bf16 As[2 * 16384];
    __shared__ __bf16 Bs[2 * 16384];
    const int t = threadIdx.x;
    const int nwg = gridDim.x * gridDim.y;
    const int olid = blockIdx.x + gridDim.x * blockIdx.y;
    const int nid = swz8(olid, nwg);
    const int jt = nid % 11, it = nid / 11;
    const int i0 = it * 256, j0 = jt * 256;
    const int lane = t & 63, wv = t >> 6;
    const int wrow = wv >> 2, wcol = wv & 3;
    const int l15 = lane & 15, hi = lane >> 4;

    f32x4 zero = {0.f, 0.f, 0.f, 0.f};
    f32x4 acc[8][4];
#pragma unroll
    for (int m = 0; m < 8; ++m)
#pragma unroll
        for (int n = 0; n < 4; ++n) acc[m][n] = zero;

    MK_OFFS(8, 128);

    const unsigned short *aB0, *aB1, *bB0, *bB1;
    {
        int P0 = t >> 2, P1 = (t + 512) >> 2;
        int g0 = GLOB(P0), g1 = GLOB(P1);
        int lc0 = (t & 3) ^ G2P(P0), lc1 = (t & 3) ^ G2P(P1);
        int ia0 = i0 + g0; if (ia0 > nloc - 1) ia0 = nloc - 1;
        int ia1 = i0 + g1; if (ia1 > nloc - 1) ia1 = nloc - 1;
        int jb0 = j0 + g0; if (jb0 > NM1_ - 1) jb0 = NM1_ - 1;
        int jb1 = j0 + g1; if (jb1 > NM1_ - 1) jb1 = NM1_ - 1;
        aB0 = AF + (size_t)ia0 * D_ + lc0 * 8;
        aB1 = AF + (size_t)ia1 * D_ + lc1 * 8;
        bB0 = attw + (size_t)jb0 * D_ + lc0 * 8;
        bB1 = attw + (size_t)jb1 * D_ + lc1 * 8;
    }
#define STAGE_A(buf, kh, kt) { \
    GLD16(aB0 + (kt) * 64 + (kh) * 32, As + (buf) * 16384 + (kh) * 8192 + t * 8); \
    GLD16(aB1 + (kt) * 64 + (kh) * 32, As + (buf) * 16384 + (kh) * 8192 + (t + 512) * 8); }
#define STAGE_B(buf, kh, kt) { \
    GLD16(bB0 + (kt) * 64 + (kh) * 32, Bs + (buf) * 16384 + (kh) * 8192 + t * 8); \
    GLD16(bB1 + (kt) * 64 + (kh) * 32, Bs + (buf) * 16384 + (kh) * 8192 + (t + 512) * 8); }

    bf16x8 a[8], b0, b1;
    GEMM_PROLOGUE();
    GEMM_LOOP(11, 8);         // D_/64
#undef STAGE_A
#undef STAGE_B

    const int r0 = i0 % N_;   // hoisted: one modulo per thread
#pragma unroll
    for (int m = 0; m < 8; ++m) {
        int db = wrow * 128 + m * 16 + hi * 4;
        int ib = i0 + db;
#pragma unroll
        for (int n = 0; n < 4; ++n) {
            int j = j0 + wcol * 64 + n * 16 + l15;
            if (j < NM1_) {
                float bias = bf2f(attb[j]);
#pragma unroll
                for (int q = 0; q < 4; ++q) {
                    int ii = ib + q;
                    if (ii < nloc) {
                        int r = r0 + db + q;
                        if (r >= N_) r -= N_;
                        int c = j + (j >= r);
                        Mbf[(size_t)ii * PK_ + c] = f2bf(acc[m][n][q] + bias);
                    }
                }
            }
        }
    }
}

// ---------------- K3b: bf16 row softmax IN PLACE (stride PK_, zero pad) + f32 M to d_out
__global__ __launch_bounds__(256) void k_softmax(unsigned short* __restrict__ Mbf,
                                                 float* __restrict__ Mout,
                                                 int row_base) {
    const int il = blockIdx.x;
    const int r = il % N_;
    unsigned short* srow = Mbf + (size_t)il * PK_;
    float* orow = Mout + (size_t)(row_base + il) * N_;
    const int t = threadIdx.x;
    float f[16];
#pragma unroll
    for (int q = 0; q < 2; ++q) {
        int c8 = t + 256 * q;
        if (c8 < N_ / 8) {
            uint4 u = *(const uint4*)(srow + c8 * 8);
            const unsigned short* pu = (const unsigned short*)&u;
#pragma unroll
            for (int e = 0; e < 8; ++e) {
                int c = c8 * 8 + e;
                float v = bf2f(pu[e]);
                f[q * 8 + e] = (c == r) ? -1e30f : v;
            }
        } else {
#pragma unroll
            for (int e = 0; e < 8; ++e) f[q * 8 + e] = -1e30f;
        }
    }
    float m = -1e30f;
#pragma unroll
    for (int q = 0; q < 16; ++q) m = fmaxf(m, f[q]);
#pragma unroll
    for (int off = 32; off >= 1; off >>= 1) m = fmaxf(m, __shfl_xor(m, off, 64));
    __shared__ float red[4];
    if ((t & 63) == 0) red[t >> 6] = m;
    __syncthreads();
    m = fmaxf(fmaxf(red[0], red[1]), fmaxf(red[2], red[3]));

    float s = 0.f;
#pragma unroll
    for (int q = 0; q < 16; ++q) { float e = __expf(f[q] - m); f[q] = e; s += e; }
#pragma unroll
    for (int off = 32; off >= 1; off >>= 1) s += __shfl_xor(s, off, 64);
    __shared__ float red2[4];
    if ((t & 63) == 0) red2[t >> 6] = s;
    __syncthreads();
    s = red2[0] + red2[1] + red2[2] + red2[3];
    float inv = 1.0f / s;
#pragma unroll
    for (int q = 0; q < 2; ++q) {
        int c8 = t + 256 * q;
        if (c8 < N_ / 8) {
            float o[8];
            union { unsigned short u[8]; uint4 v; } pb;
#pragma unroll
            for (int e = 0; e < 8; ++e) {
                o[e] = f[q * 8 + e] * inv;     // diag: exp(-1e30-m)=0 -> exact 0
                pb.u[e] = f2bf(o[e]);
            }
            float4 o0 = {o[0], o[1], o[2], o[3]};
            float4 o1 = {o[4], o[5], o[6], o[7]};
            *(float4*)(orow + c8 * 8) = o0;
            *(float4*)(orow + c8 * 8 + 4) = o1;
            *(uint4*)(srow + c8 * 8) = pb.v;
        }
    }
    if (t < 4) {
        uint4 z = {0u, 0u, 0u, 0u};
        *(uint4*)(srow + N_ + t * 8) = z;
    }
}

// ---------------- K4: MFMA att_feat = Mbf @ AF (8-phase, M=192 tiles)
__global__ __launch_bounds__(512, 1) void k_attgemm(const unsigned short* __restrict__ Mbf,
                                                    const unsigned short* __restrict__ AFT,
                                                    unsigned short* __restrict__ ATF) {
    __shared__ __bf16 As[2 * 16384];
    __shared__ __bf16 Bs[2 * 16384];
    const int t = threadIdx.x;
    const int nwg = gridDim.x * gridDim.y * gridDim.z;
    const int olid = blockIdx.x + gridDim.x * (blockIdx.y + gridDim.y * blockIdx.z);
    const int nid = swz8(olid, nwg);
    const int jt = nid % 3, it = (nid / 3) % 15, bl = nid / 45;
    const int i0 = it * 192, j0 = jt * 256;
    const int lane = t & 63, wv = t >> 6;
    const int wrow = wv >> 2, wcol = wv & 3;
    const int l15 = lane & 15, hi = lane >> 4;

    f32x4 zero = {0.f, 0.f, 0.f, 0.f};
    f32x4 acc[6][4];
#pragma unroll
    for (int m = 0; m < 6; ++m)
#pragma unroll
        for (int n = 0; n < 4; ++n) acc[m][n] = zero;

    MK_OFFS(6, 96);

    const unsigned short *aB0, *aB1, *bB0, *bB1;
    {
        int P0 = t >> 2, P1 = (t + 512) >> 2;
        int g0 = GLOB(P0), g1 = GLOB(P1);
        int lc0 = (t & 3) ^ G2P(P0), lc1 = (t & 3) ^ G2P(P1);
        int ia0 = i0 + g0; if (ia0 > N_ - 1) ia0 = N_ - 1;
        int ia1 = i0 + g1; if (ia1 > N_ - 1) ia1 = N_ - 1;
        int jb0 = j0 + g0; if (jb0 > D_ - 1) jb0 = D_ - 1;
        int jb1 = j0 + g1; if (jb1 > D_ - 1) jb1 = D_ - 1;
        aB0 = Mbf + ((size_t)bl * N_ + ia0) * PK_ + lc0 * 8;
        aB1 = Mbf + ((size_t)bl * N_ + ia1) * PK_ + lc1 * 8;
        bB0 = AFT + ((size_t)bl * D_ + jb0) * PK_ + lc0 * 8;
        bB1 = AFT + ((size_t)bl * D_ + jb1) * PK_ + lc1 * 8;
    }
#define STAGE_A(buf, kh, kt) { \
    GLD16(aB0 + (kt) * 64 + (kh) * 32, As + (buf) * 16384 + (kh) * 8192 + t * 8); \
    GLD16(aB1 + (kt) * 64 + (kh) * 32, As + (buf) * 16384 + (kh) * 8192 + (t + 512) * 8); }
#define STAGE_B(buf, kh, kt) { \
    GLD16(bB0 + (kt) * 64 + (kh) * 32, Bs + (buf) * 16384 + (kh) * 8192 + t * 8); \
    GLD16(bB1 + (kt) * 64 + (kh) * 32, Bs + (buf) * 16384 + (kh) * 8192 + (t + 512) * 8); }

    bf16x8 a[6], b0, b1;
    GEMM_PROLOGUE();
    GEMM_LOOP(44, 6);         // PK_/64
#undef STAGE_A
#undef STAGE_B

#pragma unroll
    for (int m = 0; m < 6; ++m) {
        int rb = i0 + wrow * 96 + m * 16 + hi * 4;
#pragma unroll
        for (int n = 0; n < 4; ++n) {
            int d = j0 + wcol * 64 + n * 16 + l15;
            if (d < D_) {
#pragma unroll
                for (int q = 0; q < 4; ++q) {
                    int rr = rb + q;
                    if (rr < N_)
                        ATF[((size_t)(bl * N_ + rr)) * D_ + d] = f2bf(acc[m][n][q]);
                }
            }
        }
    }
}

// ---------------- K5: MFMA heads + fused props epilogue (f32 out)
__global__ __launch_bounds__(256) void k_head(const unsigned short* __restrict__ ATF,
                                              const unsigned short* __restrict__ AF,
                                              const unsigned short* __restrict__ clsw,
                                              const unsigned short* __restrict__ clsb,
                                              const unsigned short* __restrict__ regw,
                                              const unsigned short* __restrict__ regb,
                                              const unsigned short* __restrict__ anch,
                                              float* __restrict__ props,
                                              int row_base, int nloc) {
    __shared__ __bf16 As2[128 * 32];
    __shared__ __bf16 Ws[80 * 32];
    const int t = threadIdx.x;
    const int i0 = blockIdx.x * 128;
    const int lane = t & 63, wv = t >> 6;
    const int l15 = lane & 15, hi8 = (lane >> 4) * 8;

    f32x4 zero = {0.f, 0.f, 0.f, 0.f};
    f32x4 acc[2][5];
#pragma unroll
    for (int m = 0; m < 2; ++m)
#pragma unroll
        for (int n = 0; n < 5; ++n) acc[m][n] = zero;

    const int s0 = t, s1 = t + 256;
    const int ar0 = s0 >> 2, ac0 = (s0 & 3) * 8;
    const int ar1 = s1 >> 2, ac1 = (s1 & 3) * 8;
    int ir0 = i0 + ar0; if (ir0 > nloc - 1) ir0 = nloc - 1;
    int ir1 = i0 + ar1; if (ir1 > nloc - 1) ir1 = nloc - 1;
    const unsigned short* w0base = (ar0 < 2) ? (clsw + (size_t)ar0 * D2_)
                                             : (regw + (size_t)(ar0 - 2) * D2_);
    int r1 = 64 + (t >> 2);
    int rc = r1 < 75 ? r1 : 74;
    const unsigned short* w1base = regw + (size_t)(rc - 2) * D2_;
    const int w1c = (t & 3) * 8;

    for (int p = 0; p < 2; ++p) {
        const unsigned short* Asrc = (p == 0) ? ATF : AF;
        const int wcol = p * D_;
        for (int k0 = 0; k0 < D_; k0 += 32) {
            GLD16(Asrc + (size_t)ir0 * D_ + ac0 + k0, As2 + s0 * 8);
            GLD16(Asrc + (size_t)ir1 * D_ + ac1 + k0, As2 + s1 * 8);
            GLD16(w0base + wcol + k0 + ac0, Ws + s0 * 8);
            if (t < 64) GLD16(w1base + wcol + k0 + w1c, Ws + (size_t)(256 + t) * 8);
            __syncthreads();
            bf16x8 a[2], bb[5];
#pragma unroll
            for (int m = 0; m < 2; ++m)
                a[m] = *(const bf16x8*)(As2 + (wv * 32 + m * 16 + l15) * 32 + hi8);
#pragma unroll
            for (int n = 0; n < 5; ++n)
                bb[n] = *(const bf16x8*)(Ws + (n * 16 + l15) * 32 + hi8);
#pragma unroll
            for (int m = 0; m < 2; ++m)
#pragma unroll
                for (int n = 0; n < 5; ++n)
                    acc[m][n] = __builtin_amdgcn_mfma_f32_16x16x32_bf16(a[m], bb[n], acc[m][n], 0, 0, 0);
            __syncthreads();
        }
    }

#pragma unroll
    for (int m = 0; m < 2; ++m) {
        int ib = i0 + wv * 32 + m * 16 + (lane >> 4) * 4;
#pragma unroll
        for (int n = 0; n < 5; ++n) {
            int j = n * 16 + l15;
            if (j < 75) {
#pragma unroll
                for (int q = 0; q < 4; ++q) {
                    int i = ib + q;
                    if (i < nloc) {
                        size_t g = (size_t)(row_base + i);
                        int nn = i % N_;
                        float v = acc[m][n][q];
                        if (j < 2) {
                            props[g * PW_ + j] = v + bf2f(clsb[j]);
                            props[g * PW_ + 2 + j] = bf2f(anch[(size_t)nn * PW_ + 2 + j]);
                        } else {
                            int tt = j - 2;
                            props[g * PW_ + 4 + tt] = v + bf2f(regb[tt]) + bf2f(anch[(size_t)nn * PW_ + 4 + tt]);
                        }
                    }
                }
            }
        }
    }
}

extern "C" void kernel_launch(void* const* d_in, const int* in_sizes, int n_in,
                              void* d_out, int out_size, void* d_ws, size_t ws_size,
                              hipStream_t stream) {
    (void)in_sizes; (void)n_in; (void)out_size;

    float* props = (float*)d_out;
    float* Mbuf  = props + (size_t)ROWS_ * PW_;

    char* ws = (char*)d_ws;
    int* flags = (int*)(ws + OFF_FLAGS);
    float* feat = (float*)(ws + OFF_FEAT);
    char* canon = ws + OFF_CANON;
    unsigned short* cx    = (unsigned short*)(canon + C_X);
    unsigned short* cattw = (unsigned short*)(canon + C_ATTW);
    unsigned short* ccw   = (unsigned short*)(canon + C_CW);
    unsigned short* canch = (unsigned short*)(canon + C_ANCH);
    unsigned short* cclsw = (unsigned short*)(canon + C_CLSW);
    unsigned short* cregw = (unsigned short*)(canon + C_REGW);
    unsigned short* ccb   = (unsigned short*)(canon + C_CB);
    unsigned short* cattb = (unsigned short*)(canon + C_ATTB);
    unsigned short* cclsb = (unsigned short*)(canon + C_CLSB);
    unsigned short* cregb = (unsigned short*)(canon + C_REGB);
    int* ccut = (int*)(canon + C_CUT);
    int* cmsk = (int*)(canon + C_MASK);

    const size_t base = (size_t)(12u << 20);
    const size_t per  = ((size_t)N_ * D_ * 2) * 2 + (size_t)D_ * PK_ * 2 + (size_t)N_ * PK_ * 2;
    int CN = 1;
    for (int c = 16; c >= 1; c >>= 1)
        if (ws_size >= base + (size_t)c * per) { CN = c; break; }
    unsigned short* AF  = (unsigned short*)(ws + base);
    unsigned short* AFT = AF  + (size_t)CN * N_ * D_;
    unsigned short* ATF = AFT + (size_t)CN * D_ * PK_;
    unsigned short* Mbf = ATF + (size_t)CN * N_ * D_;

    k_detect<<<dim3(1), dim3(256), 0, stream>>>((const unsigned int*)d_in[3],
                                                (const unsigned int*)d_in[10],
                                                (const unsigned int*)d_in[11], flags);
    k_canon_f<<<dim3(1024), dim3(256), 0, stream>>>(d_in[0], d_in[1], d_in[2], d_in[3], d_in[4],
                                                    d_in[5], d_in[6], d_in[7], d_in[8], d_in[9],
                                                    canon, flags);
    k_canon_i<<<dim3(120), dim3(256), 0, stream>>>(d_in[10], d_in[11], canon, flags);
    k_conv<<<dim3(880), dim3(256), 0, stream>>>(cx, ccw, ccb, feat);

    const int nchunk = 16 / CN;
    for (int c = 0; c < nchunk; ++c) {
        const int bb = c * CN;
        const int rb = bb * N_;
        const int nl = CN * N_;
        const int it128 = (nl + 127) / 128;
        const int it256 = (nl + 255) / 256;
        const int at192 = (N_ + 191) / 192;   // 15
        k_gather_af<<<dim3(N_, CN), dim3(256), 0, stream>>>(feat, ccut, cmsk, AF, bb);
        k_gather_aft<<<dim3(D_, CN), dim3(256), 0, stream>>>(feat, ccut, cmsk, AFT, bb);
        k_scores<<<dim3(11, it256), dim3(512), 0, stream>>>(AF, cattw, cattb, Mbf, nl);
        k_softmax<<<dim3(nl), dim3(256), 0, stream>>>(Mbf, Mbuf, rb);
        k_attgemm<<<dim3(3, at192, CN), dim3(512), 0, stream>>>(Mbf, AFT, ATF);
        k_head<<<dim3(it128), dim3(256), 0, stream>>>(ATF, AF, cclsw, cclsb, cregw, cregb,
                                                      canch, props, rb, nl);
    }
}

// Round 18
// 969.524 us; speedup vs baseline: 1.0276x; 1.0094x over previous
//
#include <hip/hip_runtime.h>

#define B_    16
#define CIN_  512
#define CF_   64
#define FH_   11
#define FW_   20
#define N_    2784
#define NM1_  2783
#define PK_   2816
#define D_    704
#define D2_   1408
#define ROWS_ 44544
#define PW_   77

// ---- input element counts
#define NX_     1802240
#define NCW_    32768
#define NCB_    64
#define NATTW_  1959232
#define NATTB_  2783
#define NCLSW_  2816
#define NCLSB_  2
#define NREGW_  102784
#define NREGB_  73
#define NANCH_  214368
#define NCUT_   30624

// ---- canonical ws layout (byte offsets)
#define OFF_FLAGS   0u
#define OFF_FEAT    256u
#define OFF_CANON   (1u<<20)
#define C_X      0u
#define C_ATTW   3604480u
#define C_CW     7522944u
#define C_ANCH   7588480u
#define C_CLSW   8017216u
#define C_REGW   8022848u
#define C_CB     8228416u
#define C_ATTB   8228544u
#define C_CLSB   8234112u
#define C_REGB   8234128u
#define C_CUT    8234288u
#define C_MASK   8356784u

typedef __bf16 bf16x8 __attribute__((ext_vector_type(8)));
typedef float  f32x4  __attribute__((ext_vector_type(4)));

typedef __attribute__((address_space(1))) void g_void;
typedef __attribute__((address_space(3))) void l_void;
#define GLD16(gp, lp) __builtin_amdgcn_global_load_lds((g_void*)(gp), (l_void*)(lp), 16, 0, 0)

// row permutation + chunk swizzle for 64B-row K-half LDS tiles
#define PHYS(R)  ((((R) & 1) << 7) | ((R) >> 1))
#define GLOB(P)  ((((P) & 127) << 1) | ((P) >> 7))
#define G2P(P)   (((P) + ((P) >> 1)) & 3)

__device__ __forceinline__ float bf2f(unsigned short u) {
    union { unsigned int u; float f; } v; v.u = ((unsigned int)u) << 16; return v.f;
}
__device__ __forceinline__ unsigned short f2bf(float f) {
    union { float f; unsigned int u; } v; v.f = f;
    unsigned int x = v.u;
    return (unsigned short)((x + 0x7FFFu + ((x >> 16) & 1u)) >> 16);
}

// m204 bijective XCD swizzle
__device__ __forceinline__ int swz8(int olid, int nwg) {
    int xcd = olid & 7, pos = olid >> 3;
    int q = nwg >> 3, r = nwg & 7;
    int off = (xcd < r) ? xcd * (q + 1) : r * (q + 1) + (xcd - r) * q;
    return off + pos;
}

// ---------------- K0: dtype detection
__global__ __launch_bounds__(256) void k_detect(const unsigned int* __restrict__ attw,
                                                const unsigned int* __restrict__ cut,
                                                const unsigned int* __restrict__ msk,
                                                int* __restrict__ flags) {
    __shared__ int cnt[3];
    int t = threadIdx.x;
    if (t < 3) cnt[t] = 0;
    __syncthreads();
    int c0 = 0, c1 = 0, c2 = 0;
    for (int i = t; i < 2048; i += 256) {
        unsigned int e = (attw[i] >> 7) & 0xFFu;
        if (e >= 127u) c0++;
    }
    for (int i = t; i < 4096; i += 256) if (cut[i] >= 32u) c1++;
    for (int i = t; i < 4096; i += 256) if (msk[i] >= 2u)  c2++;
    atomicAdd(&cnt[0], c0); atomicAdd(&cnt[1], c1); atomicAdd(&cnt[2], c2);
    __syncthreads();
    if (t == 0) {
        flags[0] = cnt[0] > 64;
        flags[1] = cnt[1] > 64;
        flags[2] = cnt[2] > 64;
        flags[3] = 0;
    }
}

// ---------------- K0b: canonicalize float inputs to bf16
__device__ __forceinline__ void cvt_arr(const void* s, unsigned short* d, int n, int isf32,
                                        int tid, int stride) {
    if (isf32) {
        const float* p = (const float*)s;
        for (int i = tid; i < n; i += stride) d[i] = f2bf(p[i]);
    } else {
        const unsigned short* p = (const unsigned short*)s;
        for (int i = tid; i < n; i += stride) d[i] = p[i];
    }
}

__global__ __launch_bounds__(256) void k_canon_f(const void* sx, const void* scw, const void* scb,
                                                 const void* sattw, const void* sattb,
                                                 const void* sclsw, const void* sclsb,
                                                 const void* sregw, const void* sregb,
                                                 const void* sanch, char* canon,
                                                 const int* __restrict__ flags) {
    const int isf32 = flags[0];
    const int tid = blockIdx.x * 256 + threadIdx.x;
    const int stride = gridDim.x * 256;
    cvt_arr(sx,    (unsigned short*)(canon + C_X),    NX_,    isf32, tid, stride);
    cvt_arr(sattw, (unsigned short*)(canon + C_ATTW), NATTW_, isf32, tid, stride);
    cvt_arr(scw,   (unsigned short*)(canon + C_CW),   NCW_,   isf32, tid, stride);
    cvt_arr(sanch, (unsigned short*)(canon + C_ANCH), NANCH_, isf32, tid, stride);
    cvt_arr(sclsw, (unsigned short*)(canon + C_CLSW), NCLSW_, isf32, tid, stride);
    cvt_arr(sregw, (unsigned short*)(canon + C_REGW), NREGW_, isf32, tid, stride);
    cvt_arr(scb,   (unsigned short*)(canon + C_CB),   NCB_,   isf32, tid, stride);
    cvt_arr(sattb, (unsigned short*)(canon + C_ATTB), NATTB_, isf32, tid, stride);
    cvt_arr(sclsb, (unsigned short*)(canon + C_CLSB), NCLSB_, isf32, tid, stride);
    cvt_arr(sregb, (unsigned short*)(canon + C_REGB), NREGB_, isf32, tid, stride);
}

// ---------------- K0c: canonicalize int inputs to int32
__global__ __launch_bounds__(256) void k_canon_i(const void* scut, const void* smsk,
                                                 char* canon, const int* __restrict__ flags) {
    const int cutb = flags[1], mskb = flags[2];
    int* ccut = (int*)(canon + C_CUT);
    int* cmsk = (int*)(canon + C_MASK);
    const int tid = blockIdx.x * 256 + threadIdx.x;
    const int stride = gridDim.x * 256;
    for (int i = tid; i < NCUT_; i += stride) {
        ccut[i] = cutb ? (int)((const unsigned char*)scut)[i] : ((const int*)scut)[i];
        int m = mskb ? (int)((const unsigned char*)smsk)[i] : ((const int*)smsk)[i];
        cmsk[i] = (m != 0);
    }
}

// ---------------- K1: 1x1 conv
__global__ __launch_bounds__(256) void k_conv(const unsigned short* __restrict__ x,
                                              const unsigned short* __restrict__ cw,
                                              const unsigned short* __restrict__ cb,
                                              float* __restrict__ feat) {
    int idx = blockIdx.x * 256 + threadIdx.x;
    int w = idx % FW_;
    int h = (idx / FW_) % FH_;
    int o = (idx / (FW_ * FH_)) % CF_;
    int b = idx / (FW_ * FH_ * CF_);
    const unsigned short* xp = x + ((size_t)(b * CIN_) * FH_ + h) * FW_ + w;
    const unsigned short* wp = cw + (size_t)o * CIN_;
    float acc = bf2f(cb[o]);
#pragma unroll 8
    for (int c = 0; c < CIN_; ++c)
        acc += bf2f(xp[(size_t)c * (FH_ * FW_)]) * bf2f(wp[c]);
    feat[idx] = acc;
}

// ---------------- K2a: AF chunk
__global__ __launch_bounds__(256) void k_gather_af(const float* __restrict__ feat,
                                                   const int* __restrict__ cut,
                                                   const int* __restrict__ inv,
                                                   unsigned short* __restrict__ AF,
                                                   int batch_base) {
    int n = blockIdx.x, bl = blockIdx.y;
    int b = batch_base + bl;
    __shared__ int cu[FH_];
    __shared__ int iv[FH_];
    int t = threadIdx.x;
    if (t < FH_) { cu[t] = cut[n * FH_ + t]; iv[t] = inv[n * FH_ + t]; }
    __syncthreads();
    unsigned short* out = AF + ((size_t)(bl * N_ + n)) * D_;
    for (int d = t; d < D_; d += 256) {
        int c = d / FH_, h = d - c * FH_;
        float v = iv[h] ? 0.f : feat[((b * CF_ + c) * FH_ + h) * FW_ + cu[h]];
        out[d] = f2bf(v);
    }
}

// ---------------- K2b: AFT chunk (stride PK_, pad cols zeroed)
__global__ __launch_bounds__(256) void k_gather_aft(const float* __restrict__ feat,
                                                    const int* __restrict__ cut,
                                                    const int* __restrict__ inv,
                                                    unsigned short* __restrict__ AFT,
                                                    int batch_base) {
    int d = blockIdx.x, bl = blockIdx.y;
    int b = batch_base + bl;
    int c = d / FH_, h = d - c * FH_;
    const float* fp = feat + ((b * CF_ + c) * FH_ + h) * FW_;
    unsigned short* out = AFT + ((size_t)(bl * D_ + d)) * PK_;
    for (int n = threadIdx.x; n < PK_; n += 256) {
        float v = 0.f;
        if (n < N_) {
            int w = cut[n * FH_ + h];
            v = inv[n * FH_ + h] ? 0.f : fp[w];
        }
        out[n] = f2bf(v);
    }
}

// ======== shared 8-phase GEMM body (512 thr, 8 waves 2x4, BK=64) ========
// MC = A-frags/wave (8 -> M=256, span 128; 6 -> M=192, span 96).
// LDS per matrix: [2 buf][2 khalf][256 phys-rows x 32 K].

#define GEMM_PROLOGUE()                                                               \
    STAGE_A(0, 0, 0); STAGE_B(0, 0, 0); STAGE_A(0, 1, 0); STAGE_B(0, 1, 0);           \
    STAGE_A(1, 0, 1); STAGE_B(1, 0, 1);

#define RD_A(kh, MC)                                                                  \
    _Pragma("unroll")                                                                 \
    for (int m = 0; m < (MC); ++m)                                                    \
        a[m] = *(const bf16x8*)(As + cur * 16384 + (kh) * 8192 + aoff[m]);

#define RD_B(kh, n0)                                                                  \
    {                                                                                 \
        b0 = *(const bf16x8*)(Bs + cur * 16384 + (kh) * 8192 + boff[(n0)]);           \
        b1 = *(const bf16x8*)(Bs + cur * 16384 + (kh) * 8192 + boff[(n0) + 1]);       \
    }

#define MFMAX(n0, MC)                                                                 \
    asm volatile("s_waitcnt lgkmcnt(0)" ::: "memory");                                \
    __builtin_amdgcn_sched_barrier(0);                                                \
    __builtin_amdgcn_s_setprio(1);                                                    \
    _Pragma("unroll")                                                                 \
    for (int m = 0; m < (MC); ++m) {                                                  \
        acc[m][(n0)] = __builtin_amdgcn_mfma_f32_16x16x32_bf16(a[m], b0, acc[m][(n0)], 0, 0, 0); \
        acc[m][(n0) + 1] = __builtin_amdgcn_mfma_f32_16x16x32_bf16(a[m], b1, acc[m][(n0) + 1], 0, 0, 0); \
    }                                                                                 \
    __builtin_amdgcn_s_setprio(0);

// full-stage boundary: all waves carry 8 outstanding loads in steady state
#define BOUNDARY(tail)                                                                \
    if (tail) asm volatile("s_waitcnt vmcnt(0)" ::: "memory");                        \
    else      asm volatile("s_waitcnt vmcnt(8)" ::: "memory");                        \
    __builtin_amdgcn_sched_barrier(0);                                                \
    __builtin_amdgcn_s_barrier();

// attgemm boundary: waves 6-7 skip A staging (only 4 outstanding B loads) -> vmcnt(4)
#define BOUNDARY_AG(tail)                                                             \
    if (tail) asm volatile("s_waitcnt vmcnt(0)" ::: "memory");                        \
    else if (wv < 6) asm volatile("s_waitcnt vmcnt(8)" ::: "memory");                 \
    else asm volatile("s_waitcnt vmcnt(4)" ::: "memory");                             \
    __builtin_amdgcn_sched_barrier(0);                                                \
    __builtin_amdgcn_s_barrier();

#define GEMM_LOOP(NT, MC, BND)                                                        \
    for (int tt = 0; tt < (NT); ++tt) {                                               \
        const int cur = tt & 1, nxt = cur ^ 1;                                        \
        const bool tail = (tt >= (NT) - 2);                                           \
        BND(tail);                                                                    \
        RD_A(0, MC); RD_B(0, 0);                                                      \
        if (tt + 1 < (NT)) STAGE_A(nxt, 1, tt + 1);                                   \
        MFMAX(0, MC);                                                                 \
        __builtin_amdgcn_s_barrier();                                                 \
        RD_B(0, 2);                                                                   \
        if (tt + 1 < (NT)) STAGE_B(nxt, 1, tt + 1);                                   \
        MFMAX(2, MC);                                                                 \
        __builtin_amdgcn_s_barrier();                                                 \
        BND(tail);                                                                    \
        RD_A(1, MC); RD_B(1, 0);                                                      \
        if (tt + 2 < (NT)) STAGE_A(cur, 0, tt + 2);                                   \
        MFMAX(0, MC);                                                                 \
        __builtin_amdgcn_s_barrier();                                                 \
        RD_B(1, 2);                                                                   \
        if (tt + 2 < (NT)) STAGE_B(cur, 0, tt + 2);                                   \
        MFMAX(2, MC);                                                                 \
    }

#define MK_OFFS(MC, SPAN)                                                             \
    int aoff[MC], boff[4];                                                            \
    _Pragma("unroll")                                                                 \
    for (int m = 0; m < (MC); ++m) {                                                  \
        int R = wrow * (SPAN) + m * 16 + l15;                                         \
        int P = PHYS(R);                                                              \
        aoff[m] = P * 32 + ((hi ^ G2P(P)) * 8);                                       \
    }                                                                                 \
    _Pragma("unroll")                                                                 \
    for (int n = 0; n < 4; ++n) {                                                     \
        int R = wcol * 64 + n * 16 + l15;                                             \
        int P = PHYS(R);                                                              \
        boff[n] = P * 32 + ((hi ^ G2P(P)) * 8);                                       \
    }

// ---------------- K3a: MFMA scores GEMM (8-phase, M=256 tiles, hoisted modulo)
__global__ __launch_bounds__(512, 1) void k_scores(const unsigned short* __restrict__ AF,
                                                   const unsigned short* __restrict__ attw,
                                                   const unsigned short* __restrict__ attb,
                                                   unsigned short* __restrict__ Mbf,
                                                   int nloc) {
    __shared__ __bf16 As[2 * 16384];
    __shared__ __bf16 Bs[2 * 16384];
    const int t = threadIdx.x;
    const int nwg = gridDim.x * gridDim.y;
    const int olid = blockIdx.x + gridDim.x * blockIdx.y;
    const int nid = swz8(olid, nwg);
    const int jt = nid % 11, it = nid / 11;
    const int i0 = it * 256, j0 = jt * 256;
    const int lane = t & 63, wv = t >> 6;
    const int wrow = wv >> 2, wcol = wv & 3;
    const int l15 = lane & 15, hi = lane >> 4;

    f32x4 zero = {0.f, 0.f, 0.f, 0.f};
    f32x4 acc[8][4];
#pragma unroll
    for (int m = 0; m < 8; ++m)
#pragma unroll
        for (int n = 0; n < 4; ++n) acc[m][n] = zero;

    MK_OFFS(8, 128);

    const unsigned short *aB0, *aB1, *bB0, *bB1;
    {
        int P0 = t >> 2, P1 = (t + 512) >> 2;
        int g0 = GLOB(P0), g1 = GLOB(P1);
        int lc0 = (t & 3) ^ G2P(P0), lc1 = (t & 3) ^ G2P(P1);
        int ia0 = i0 + g0; if (ia0 > nloc - 1) ia0 = nloc - 1;
        int ia1 = i0 + g1; if (ia1 > nloc - 1) ia1 = nloc - 1;
        int jb0 = j0 + g0; if (jb0 > NM1_ - 1) jb0 = NM1_ - 1;
        int jb1 = j0 + g1; if (jb1 > NM1_ - 1) jb1 = NM1_ - 1;
        aB0 = AF + (size_t)ia0 * D_ + lc0 * 8;
        aB1 = AF + (size_t)ia1 * D_ + lc1 * 8;
        bB0 = attw + (size_t)jb0 * D_ + lc0 * 8;
        bB1 = attw + (size_t)jb1 * D_ + lc1 * 8;
    }
#define STAGE_A(buf, kh, kt) { \
    GLD16(aB0 + (kt) * 64 + (kh) * 32, As + (buf) * 16384 + (kh) * 8192 + t * 8); \
    GLD16(aB1 + (kt) * 64 + (kh) * 32, As + (buf) * 16384 + (kh) * 8192 + (t + 512) * 8); }
#define STAGE_B(buf, kh, kt) { \
    GLD16(bB0 + (kt) * 64 + (kh) * 32, Bs + (buf) * 16384 + (kh) * 8192 + t * 8); \
    GLD16(bB1 + (kt) * 64 + (kh) * 32, Bs + (buf) * 16384 + (kh) * 8192 + (t + 512) * 8); }

    bf16x8 a[8], b0, b1;
    GEMM_PROLOGUE();
    GEMM_LOOP(11, 8, BOUNDARY);    // D_/64
#undef STAGE_A
#undef STAGE_B

    const int r0 = i0 % N_;   // hoisted: one modulo per thread
#pragma unroll
    for (int m = 0; m < 8; ++m) {
        int db = wrow * 128 + m * 16 + hi * 4;
        int ib = i0 + db;
#pragma unroll
        for (int n = 0; n < 4; ++n) {
            int j = j0 + wcol * 64 + n * 16 + l15;
            if (j < NM1_) {
                float bias = bf2f(attb[j]);
#pragma unroll
                for (int q = 0; q < 4; ++q) {
                    int ii = ib + q;
                    if (ii < nloc) {
                        int r = r0 + db + q;
                        if (r >= N_) r -= N_;
                        int c = j + (j >= r);
                        Mbf[(size_t)ii * PK_ + c] = f2bf(acc[m][n][q] + bias);
                    }
                }
            }
        }
    }
}

// ---------------- K3b: bf16 row softmax IN PLACE (stride PK_, zero pad) + f32 M to d_out
__global__ __launch_bounds__(256) void k_softmax(unsigned short* __restrict__ Mbf,
                                                 float* __restrict__ Mout,
                                                 int row_base) {
    const int il = blockIdx.x;
    const int r = il % N_;
    unsigned short* srow = Mbf + (size_t)il * PK_;
    float* orow = Mout + (size_t)(row_base + il) * N_;
    const int t = threadIdx.x;
    float f[16];
#pragma unroll
    for (int q = 0; q < 2; ++q) {
        int c8 = t + 256 * q;
        if (c8 < N_ / 8) {
            uint4 u = *(const uint4*)(srow + c8 * 8);
            const unsigned short* pu = (const unsigned short*)&u;
#pragma unroll
            for (int e = 0; e < 8; ++e) {
                int c = c8 * 8 + e;
                float v = bf2f(pu[e]);
                f[q * 8 + e] = (c == r) ? -1e30f : v;
            }
        } else {
#pragma unroll
            for (int e = 0; e < 8; ++e) f[q * 8 + e] = -1e30f;
        }
    }
    float m = -1e30f;
#pragma unroll
    for (int q = 0; q < 16; ++q) m = fmaxf(m, f[q]);
#pragma unroll
    for (int off = 32; off >= 1; off >>= 1) m = fmaxf(m, __shfl_xor(m, off, 64));
    __shared__ float red[4];
    if ((t & 63) == 0) red[t >> 6] = m;
    __syncthreads();
    m = fmaxf(fmaxf(red[0], red[1]), fmaxf(red[2], red[3]));

    float s = 0.f;
#pragma unroll
    for (int q = 0; q < 16; ++q) { float e = __expf(f[q] - m); f[q] = e; s += e; }
#pragma unroll
    for (int off = 32; off >= 1; off >>= 1) s += __shfl_xor(s, off, 64);
    __shared__ float red2[4];
    if ((t & 63) == 0) red2[t >> 6] = s;
    __syncthreads();
    s = red2[0] + red2[1] + red2[2] + red2[3];
    float inv = 1.0f / s;
#pragma unroll
    for (int q = 0; q < 2; ++q) {
        int c8 = t + 256 * q;
        if (c8 < N_ / 8) {
            float o[8];
            union { unsigned short u[8]; uint4 v; } pb;
#pragma unroll
            for (int e = 0; e < 8; ++e) {
                o[e] = f[q * 8 + e] * inv;     // diag: exp(-1e30-m)=0 -> exact 0
                pb.u[e] = f2bf(o[e]);
            }
            float4 o0 = {o[0], o[1], o[2], o[3]};
            float4 o1 = {o[4], o[5], o[6], o[7]};
            *(float4*)(orow + c8 * 8) = o0;
            *(float4*)(orow + c8 * 8 + 4) = o1;
            *(uint4*)(srow + c8 * 8) = pb.v;
        }
    }
    if (t < 4) {
        uint4 z = {0u, 0u, 0u, 0u};
        *(uint4*)(srow + N_ + t * 8) = z;
    }
}

// ---------------- K4: MFMA att_feat = Mbf @ AF (8-phase, M=192, trimmed A staging)
__global__ __launch_bounds__(512, 1) void k_attgemm(const unsigned short* __restrict__ Mbf,
                                                    const unsigned short* __restrict__ AFT,
                                                    unsigned short* __restrict__ ATF) {
    __shared__ __bf16 As[2 * 16384];
    __shared__ __bf16 Bs[2 * 16384];
    const int t = threadIdx.x;
    const int nwg = gridDim.x * gridDim.y * gridDim.z;
    const int olid = blockIdx.x + gridDim.x * (blockIdx.y + gridDim.y * blockIdx.z);
    const int nid = swz8(olid, nwg);
    const int jt = nid % 3, it = (nid / 3) % 15, bl = nid / 45;
    const int i0 = it * 192, j0 = jt * 256;
    const int lane = t & 63, wv = t >> 6;
    const int wrow = wv >> 2, wcol = wv & 3;
    const int l15 = lane & 15, hi = lane >> 4;

    f32x4 zero = {0.f, 0.f, 0.f, 0.f};
    f32x4 acc[6][4];
#pragma unroll
    for (int m = 0; m < 6; ++m)
#pragma unroll
        for (int n = 0; n < 4; ++n) acc[m][n] = zero;

    MK_OFFS(6, 96);

    const unsigned short *aB0, *aB1, *bB0, *bB1;
    {
        int P0 = t >> 2, P1 = (t + 512) >> 2;
        int g0 = GLOB(P0), g1 = GLOB(P1);
        int lc0 = (t & 3) ^ G2P(P0), lc1 = (t & 3) ^ G2P(P1);
        int ia0 = i0 + g0; if (ia0 > N_ - 1) ia0 = N_ - 1;
        int ia1 = i0 + g1; if (ia1 > N_ - 1) ia1 = N_ - 1;
        int jb0 = j0 + g0; if (jb0 > D_ - 1) jb0 = D_ - 1;
        int jb1 = j0 + g1; if (jb1 > D_ - 1) jb1 = D_ - 1;
        aB0 = Mbf + ((size_t)bl * N_ + ia0) * PK_ + lc0 * 8;
        aB1 = Mbf + ((size_t)bl * N_ + ia1) * PK_ + lc1 * 8;
        bB0 = AFT + ((size_t)bl * D_ + jb0) * PK_ + lc0 * 8;
        bB1 = AFT + ((size_t)bl * D_ + jb1) * PK_ + lc1 * 8;
    }
// A rows 192..255 unused at M=192 -> phys rows [96,128)+[224,256) -> exactly slots
// t>=384 in both stage calls; waves 6-7 skip A entirely (wave-uniform skip).
#define STAGE_A(buf, kh, kt) { if (t < 384) { \
    GLD16(aB0 + (kt) * 64 + (kh) * 32, As + (buf) * 16384 + (kh) * 8192 + t * 8); \
    GLD16(aB1 + (kt) * 64 + (kh) * 32, As + (buf) * 16384 + (kh) * 8192 + (t + 512) * 8); } }
#define STAGE_B(buf, kh, kt) { \
    GLD16(bB0 + (kt) * 64 + (kh) * 32, Bs + (buf) * 16384 + (kh) * 8192 + t * 8); \
    GLD16(bB1 + (kt) * 64 + (kh) * 32, Bs + (buf) * 16384 + (kh) * 8192 + (t + 512) * 8); }

    bf16x8 a[6], b0, b1;
    GEMM_PROLOGUE();
    GEMM_LOOP(44, 6, BOUNDARY_AG);  // PK_/64
#undef STAGE_A
#undef STAGE_B

#pragma unroll
    for (int m = 0; m < 6; ++m) {
        int rb = i0 + wrow * 96 + m * 16 + hi * 4;
#pragma unroll
        for (int n = 0; n < 4; ++n) {
            int d = j0 + wcol * 64 + n * 16 + l15;
            if (d < D_) {
#pragma unroll
                for (int q = 0; q < 4; ++q) {
                    int rr = rb + q;
                    if (rr < N_)
                        ATF[((size_t)(bl * N_ + rr)) * D_ + d] = f2bf(acc[m][n][q]);
                }
            }
        }
    }
}

// ---------------- K5: MFMA heads + fused props epilogue (f32 out)
__global__ __launch_bounds__(256) void k_head(const unsigned short* __restrict__ ATF,
                                              const unsigned short* __restrict__ AF,
                                              const unsigned short* __restrict__ clsw,
                                              const unsigned short* __restrict__ clsb,
                                              const unsigned short* __restrict__ regw,
                                              const unsigned short* __restrict__ regb,
                                              const unsigned short* __restrict__ anch,
                                              float* __restrict__ props,
                                              int row_base, int nloc) {
    __shared__ __bf16 As2[128 * 32];
    __shared__ __bf16 Ws[80 * 32];
    const int t = threadIdx.x;
    const int i0 = blockIdx.x * 128;
    const int lane = t & 63, wv = t >> 6;
    const int l15 = lane & 15, hi8 = (lane >> 4) * 8;

    f32x4 zero = {0.f, 0.f, 0.f, 0.f};
    f32x4 acc[2][5];
#pragma unroll
    for (int m = 0; m < 2; ++m)
#pragma unroll
        for (int n = 0; n < 5; ++n) acc[m][n] = zero;

    const int s0 = t, s1 = t + 256;
    const int ar0 = s0 >> 2, ac0 = (s0 & 3) * 8;
    const int ar1 = s1 >> 2, ac1 = (s1 & 3) * 8;
    int ir0 = i0 + ar0; if (ir0 > nloc - 1) ir0 = nloc - 1;
    int ir1 = i0 + ar1; if (ir1 > nloc - 1) ir1 = nloc - 1;
    const unsigned short* w0base = (ar0 < 2) ? (clsw + (size_t)ar0 * D2_)
                                             : (regw + (size_t)(ar0 - 2) * D2_);
    int r1 = 64 + (t >> 2);
    int rc = r1 < 75 ? r1 : 74;
    const unsigned short* w1base = regw + (size_t)(rc - 2) * D2_;
    const int w1c = (t & 3) * 8;

    for (int p = 0; p < 2; ++p) {
        const unsigned short* Asrc = (p == 0) ? ATF : AF;
        const int wcol = p * D_;
        for (int k0 = 0; k0 < D_; k0 += 32) {
            GLD16(Asrc + (size_t)ir0 * D_ + ac0 + k0, As2 + s0 * 8);
            GLD16(Asrc + (size_t)ir1 * D_ + ac1 + k0, As2 + s1 * 8);
            GLD16(w0base + wcol + k0 + ac0, Ws + s0 * 8);
            if (t < 64) GLD16(w1base + wcol + k0 + w1c, Ws + (size_t)(256 + t) * 8);
            __syncthreads();
            bf16x8 a[2], bb[5];
#pragma unroll
            for (int m = 0; m < 2; ++m)
                a[m] = *(const bf16x8*)(As2 + (wv * 32 + m * 16 + l15) * 32 + hi8);
#pragma unroll
            for (int n = 0; n < 5; ++n)
                bb[n] = *(const bf16x8*)(Ws + (n * 16 + l15) * 32 + hi8);
#pragma unroll
            for (int m = 0; m < 2; ++m)
#pragma unroll
                for (int n = 0; n < 5; ++n)
                    acc[m][n] = __builtin_amdgcn_mfma_f32_16x16x32_bf16(a[m], bb[n], acc[m][n], 0, 0, 0);
            __syncthreads();
        }
    }

#pragma unroll
    for (int m = 0; m < 2; ++m) {
        int ib = i0 + wv * 32 + m * 16 + (lane >> 4) * 4;
#pragma unroll
        for (int n = 0; n < 5; ++n) {
            int j = n * 16 + l15;
            if (j < 75) {
#pragma unroll
                for (int q = 0; q < 4; ++q) {
                    int i = ib + q;
                    if (i < nloc) {
                        size_t g = (size_t)(row_base + i);
                        int nn = i % N_;
                        float v = acc[m][n][q];
                        if (j < 2) {
                            props[g * PW_ + j] = v + bf2f(clsb[j]);
                            props[g * PW_ + 2 + j] = bf2f(anch[(size_t)nn * PW_ + 2 + j]);
                        } else {
                            int tt = j - 2;
                            props[g * PW_ + 4 + tt] = v + bf2f(regb[tt]) + bf2f(anch[(size_t)nn * PW_ + 4 + tt]);
                        }
                    }
                }
            }
        }
    }
}

extern "C" void kernel_launch(void* const* d_in, const int* in_sizes, int n_in,
                              void* d_out, int out_size, void* d_ws, size_t ws_size,
                              hipStream_t stream) {
    (void)in_sizes; (void)n_in; (void)out_size;

    float* props = (float*)d_out;
    float* Mbuf  = props + (size_t)ROWS_ * PW_;

    char* ws = (char*)d_ws;
    int* flags = (int*)(ws + OFF_FLAGS);
    float* feat = (float*)(ws + OFF_FEAT);
    char* canon = ws + OFF_CANON;
    unsigned short* cx    = (unsigned short*)(canon + C_X);
    unsigned short* cattw = (unsigned short*)(canon + C_ATTW);
    unsigned short* ccw   = (unsigned short*)(canon + C_CW);
    unsigned short* canch = (unsigned short*)(canon + C_ANCH);
    unsigned short* cclsw = (unsigned short*)(canon + C_CLSW);
    unsigned short* cregw = (unsigned short*)(canon + C_REGW);
    unsigned short* ccb   = (unsigned short*)(canon + C_CB);
    unsigned short* cattb = (unsigned short*)(canon + C_ATTB);
    unsigned short* cclsb = (unsigned short*)(canon + C_CLSB);
    unsigned short* cregb = (unsigned short*)(canon + C_REGB);
    int* ccut = (int*)(canon + C_CUT);
    int* cmsk = (int*)(canon + C_MASK);

    const size_t base = (size_t)(12u << 20);
    const size_t per  = ((size_t)N_ * D_ * 2) * 2 + (size_t)D_ * PK_ * 2 + (size_t)N_ * PK_ * 2;
    int CN = 1;
    for (int c = 16; c >= 1; c >>= 1)
        if (ws_size >= base + (size_t)c * per) { CN = c; break; }
    unsigned short* AF  = (unsigned short*)(ws + base);
    unsigned short* AFT = AF  + (size_t)CN * N_ * D_;
    unsigned short* ATF = AFT + (size_t)CN * D_ * PK_;
    unsigned short* Mbf = ATF + (size_t)CN * N_ * D_;

    k_detect<<<dim3(1), dim3(256), 0, stream>>>((const unsigned int*)d_in[3],
                                                (const unsigned int*)d_in[10],
                                                (const unsigned int*)d_in[11], flags);
    k_canon_f<<<dim3(1024), dim3(256), 0, stream>>>(d_in[0], d_in[1], d_in[2], d_in[3], d_in[4],
                                                    d_in[5], d_in[6], d_in[7], d_in[8], d_in[9],
                                                    canon, flags);
    k_canon_i<<<dim3(120), dim3(256), 0, stream>>>(d_in[10], d_in[11], canon, flags);
    k_conv<<<dim3(880), dim3(256), 0, stream>>>(cx, ccw, ccb, feat);

    const int nchunk = 16 / CN;
    for (int c = 0; c < nchunk; ++c) {
        const int bb = c * CN;
        const int rb = bb * N_;
        const int nl = CN * N_;
        const int it128 = (nl + 127) / 128;
        const int it256 = (nl + 255) / 256;
        const int at192 = (N_ + 191) / 192;   // 15
        k_gather_af<<<dim3(N_, CN), dim3(256), 0, stream>>>(feat, ccut, cmsk, AF, bb);
        k_gather_aft<<<dim3(D_, CN), dim3(256), 0, stream>>>(feat, ccut, cmsk, AFT, bb);
        k_scores<<<dim3(11, it256), dim3(512), 0, stream>>>(AF, cattw, cattb, Mbf, nl);
        k_softmax<<<dim3(nl), dim3(256), 0, stream>>>(Mbf, Mbuf, rb);
        k_attgemm<<<dim3(3, at192, CN), dim3(512), 0, stream>>>(Mbf, AFT, ATF);
        k_head<<<dim3(it128), dim3(256), 0, stream>>>(ATF, AF, cclsw, cclsb, cregw, cregb,
                                                      canch, props, rb, nl);
    }
}

// Round 19
// 969.383 us; speedup vs baseline: 1.0278x; 1.0001x over previous
//
#include <hip/hip_runtime.h>

#define B_    16
#define CIN_  512
#define CF_   64
#define FH_   11
#define FW_   20
#define N_    2784
#define NM1_  2783
#define PK_   2816
#define D_    704
#define D2_   1408
#define ROWS_ 44544
#define PW_   77

// ---- input element counts
#define NX_     1802240
#define NCW_    32768
#define NCB_    64
#define NATTW_  1959232
#define NATTB_  2783
#define NCLSW_  2816
#define NCLSB_  2
#define NREGW_  102784
#define NREGB_  73
#define NANCH_  214368
#define NCUT_   30624

// ---- canonical ws layout (byte offsets)
#define OFF_FLAGS   0u
#define OFF_FEAT    256u
#define OFF_CANON   (1u<<20)
#define C_X      0u
#define C_ATTW   3604480u
#define C_CW     7522944u
#define C_ANCH   7588480u
#define C_CLSW   8017216u
#define C_REGW   8022848u
#define C_CB     8228416u
#define C_ATTB   8228544u
#define C_CLSB   8234112u
#define C_REGB   8234128u
#define C_CUT    8234288u
#define C_MASK   8356784u

typedef __bf16 bf16x8 __attribute__((ext_vector_type(8)));
typedef float  f32x4  __attribute__((ext_vector_type(4)));

typedef __attribute__((address_space(1))) void g_void;
typedef __attribute__((address_space(3))) void l_void;
#define GLD16(gp, lp) __builtin_amdgcn_global_load_lds((g_void*)(gp), (l_void*)(lp), 16, 0, 0)

// row permutation + chunk swizzle for 64B-row K-half LDS tiles
#define PHYS(R)  ((((R) & 1) << 7) | ((R) >> 1))
#define GLOB(P)  ((((P) & 127) << 1) | ((P) >> 7))
#define G2P(P)   (((P) + ((P) >> 1)) & 3)

__device__ __forceinline__ float bf2f(unsigned short u) {
    union { unsigned int u; float f; } v; v.u = ((unsigned int)u) << 16; return v.f;
}
__device__ __forceinline__ unsigned short f2bf(float f) {
    union { float f; unsigned int u; } v; v.f = f;
    unsigned int x = v.u;
    return (unsigned short)((x + 0x7FFFu + ((x >> 16) & 1u)) >> 16);
}

// m204 bijective XCD swizzle
__device__ __forceinline__ int swz8(int olid, int nwg) {
    int xcd = olid & 7, pos = olid >> 3;
    int q = nwg >> 3, r = nwg & 7;
    int off = (xcd < r) ? xcd * (q + 1) : r * (q + 1) + (xcd - r) * q;
    return off + pos;
}

// ---------------- K0: dtype detection
__global__ __launch_bounds__(256) void k_detect(const unsigned int* __restrict__ attw,
                                                const unsigned int* __restrict__ cut,
                                                const unsigned int* __restrict__ msk,
                                                int* __restrict__ flags) {
    __shared__ int cnt[3];
    int t = threadIdx.x;
    if (t < 3) cnt[t] = 0;
    __syncthreads();
    int c0 = 0, c1 = 0, c2 = 0;
    for (int i = t; i < 2048; i += 256) {
        unsigned int e = (attw[i] >> 7) & 0xFFu;
        if (e >= 127u) c0++;
    }
    for (int i = t; i < 4096; i += 256) if (cut[i] >= 32u) c1++;
    for (int i = t; i < 4096; i += 256) if (msk[i] >= 2u)  c2++;
    atomicAdd(&cnt[0], c0); atomicAdd(&cnt[1], c1); atomicAdd(&cnt[2], c2);
    __syncthreads();
    if (t == 0) {
        flags[0] = cnt[0] > 64;
        flags[1] = cnt[1] > 64;
        flags[2] = cnt[2] > 64;
        flags[3] = 0;
    }
}

// ---------------- K0b: canonicalize float inputs to bf16
__device__ __forceinline__ void cvt_arr(const void* s, unsigned short* d, int n, int isf32,
                                        int tid, int stride) {
    if (isf32) {
        const float* p = (const float*)s;
        for (int i = tid; i < n; i += stride) d[i] = f2bf(p[i]);
    } else {
        const unsigned short* p = (const unsigned short*)s;
        for (int i = tid; i < n; i += stride) d[i] = p[i];
    }
}

__global__ __launch_bounds__(256) void k_canon_f(const void* sx, const void* scw, const void* scb,
                                                 const void* sattw, const void* sattb,
                                                 const void* sclsw, const void* sclsb,
                                                 const void* sregw, const void* sregb,
                                                 const void* sanch, char* canon,
                                                 const int* __restrict__ flags) {
    const int isf32 = flags[0];
    const int tid = blockIdx.x * 256 + threadIdx.x;
    const int stride = gridDim.x * 256;
    cvt_arr(sx,    (unsigned short*)(canon + C_X),    NX_,    isf32, tid, stride);
    cvt_arr(sattw, (unsigned short*)(canon + C_ATTW), NATTW_, isf32, tid, stride);
    cvt_arr(scw,   (unsigned short*)(canon + C_CW),   NCW_,   isf32, tid, stride);
    cvt_arr(sanch, (unsigned short*)(canon + C_ANCH), NANCH_, isf32, tid, stride);
    cvt_arr(sclsw, (unsigned short*)(canon + C_CLSW), NCLSW_, isf32, tid, stride);
    cvt_arr(sregw, (unsigned short*)(canon + C_REGW), NREGW_, isf32, tid, stride);
    cvt_arr(scb,   (unsigned short*)(canon + C_CB),   NCB_,   isf32, tid, stride);
    cvt_arr(sattb, (unsigned short*)(canon + C_ATTB), NATTB_, isf32, tid, stride);
    cvt_arr(sclsb, (unsigned short*)(canon + C_CLSB), NCLSB_, isf32, tid, stride);
    cvt_arr(sregb, (unsigned short*)(canon + C_REGB), NREGB_, isf32, tid, stride);
}

// ---------------- K0c: canonicalize int inputs to int32
__global__ __launch_bounds__(256) void k_canon_i(const void* scut, const void* smsk,
                                                 char* canon, const int* __restrict__ flags) {
    const int cutb = flags[1], mskb = flags[2];
    int* ccut = (int*)(canon + C_CUT);
    int* cmsk = (int*)(canon + C_MASK);
    const int tid = blockIdx.x * 256 + threadIdx.x;
    const int stride = gridDim.x * 256;
    for (int i = tid; i < NCUT_; i += stride) {
        ccut[i] = cutb ? (int)((const unsigned char*)scut)[i] : ((const int*)scut)[i];
        int m = mskb ? (int)((const unsigned char*)smsk)[i] : ((const int*)smsk)[i];
        cmsk[i] = (m != 0);
    }
}

// ---------------- K1: 1x1 conv
__global__ __launch_bounds__(256) void k_conv(const unsigned short* __restrict__ x,
                                              const unsigned short* __restrict__ cw,
                                              const unsigned short* __restrict__ cb,
                                              float* __restrict__ feat) {
    int idx = blockIdx.x * 256 + threadIdx.x;
    int w = idx % FW_;
    int h = (idx / FW_) % FH_;
    int o = (idx / (FW_ * FH_)) % CF_;
    int b = idx / (FW_ * FH_ * CF_);
    const unsigned short* xp = x + ((size_t)(b * CIN_) * FH_ + h) * FW_ + w;
    const unsigned short* wp = cw + (size_t)o * CIN_;
    float acc = bf2f(cb[o]);
#pragma unroll 8
    for (int c = 0; c < CIN_; ++c)
        acc += bf2f(xp[(size_t)c * (FH_ * FW_)]) * bf2f(wp[c]);
    feat[idx] = acc;
}

// ---------------- K2a: AF chunk
__global__ __launch_bounds__(256) void k_gather_af(const float* __restrict__ feat,
                                                   const int* __restrict__ cut,
                                                   const int* __restrict__ inv,
                                                   unsigned short* __restrict__ AF,
                                                   int batch_base) {
    int n = blockIdx.x, bl = blockIdx.y;
    int b = batch_base + bl;
    __shared__ int cu[FH_];
    __shared__ int iv[FH_];
    int t = threadIdx.x;
    if (t < FH_) { cu[t] = cut[n * FH_ + t]; iv[t] = inv[n * FH_ + t]; }
    __syncthreads();
    unsigned short* out = AF + ((size_t)(bl * N_ + n)) * D_;
    for (int d = t; d < D_; d += 256) {
        int c = d / FH_, h = d - c * FH_;
        float v = iv[h] ? 0.f : feat[((b * CF_ + c) * FH_ + h) * FW_ + cu[h]];
        out[d] = f2bf(v);
    }
}

// ---------------- K2b: AFT chunk (stride PK_, pad cols zeroed)
__global__ __launch_bounds__(256) void k_gather_aft(const float* __restrict__ feat,
                                                    const int* __restrict__ cut,
                                                    const int* __restrict__ inv,
                                                    unsigned short* __restrict__ AFT,
                                                    int batch_base) {
    int d = blockIdx.x, bl = blockIdx.y;
    int b = batch_base + bl;
    int c = d / FH_, h = d - c * FH_;
    const float* fp = feat + ((b * CF_ + c) * FH_ + h) * FW_;
    unsigned short* out = AFT + ((size_t)(bl * D_ + d)) * PK_;
    for (int n = threadIdx.x; n < PK_; n += 256) {
        float v = 0.f;
        if (n < N_) {
            int w = cut[n * FH_ + h];
            v = inv[n * FH_ + h] ? 0.f : fp[w];
        }
        out[n] = f2bf(v);
    }
}

// ======== shared 8-phase GEMM body (512 thr, 8 waves 2x4, BK=64) ========
// MC = A-frags/wave (8 -> M=256, span 128; 6 -> M=192, span 96).
// LDS per matrix: [2 buf][2 khalf][256 phys-rows x 32 K].

#define GEMM_PROLOGUE()                                                               \
    STAGE_A(0, 0, 0); STAGE_B(0, 0, 0); STAGE_A(0, 1, 0); STAGE_B(0, 1, 0);           \
    STAGE_A(1, 0, 1); STAGE_B(1, 0, 1);

#define RD_A(kh, MC)                                                                  \
    _Pragma("unroll")                                                                 \
    for (int m = 0; m < (MC); ++m)                                                    \
        a[m] = *(const bf16x8*)(As + cur * 16384 + (kh) * 8192 + aoff[m]);

#define RD_B(kh, n0)                                                                  \
    {                                                                                 \
        b0 = *(const bf16x8*)(Bs + cur * 16384 + (kh) * 8192 + boff[(n0)]);           \
        b1 = *(const bf16x8*)(Bs + cur * 16384 + (kh) * 8192 + boff[(n0) + 1]);       \
    }

#define MFMAX(n0, MC)                                                                 \
    asm volatile("s_waitcnt lgkmcnt(0)" ::: "memory");                                \
    __builtin_amdgcn_sched_barrier(0);                                                \
    __builtin_amdgcn_s_setprio(1);                                                    \
    _Pragma("unroll")                                                                 \
    for (int m = 0; m < (MC); ++m) {                                                  \
        acc[m][(n0)] = __builtin_amdgcn_mfma_f32_16x16x32_bf16(a[m], b0, acc[m][(n0)], 0, 0, 0); \
        acc[m][(n0) + 1] = __builtin_amdgcn_mfma_f32_16x16x32_bf16(a[m], b1, acc[m][(n0) + 1], 0, 0, 0); \
    }                                                                                 \
    __builtin_amdgcn_s_setprio(0);

// full-stage boundary: all waves carry 8 outstanding loads in steady state
#define BOUNDARY(tail)                                                                \
    if (tail) asm volatile("s_waitcnt vmcnt(0)" ::: "memory");                        \
    else      asm volatile("s_waitcnt vmcnt(8)" ::: "memory");                        \
    __builtin_amdgcn_sched_barrier(0);                                                \
    __builtin_amdgcn_s_barrier();

// attgemm boundary: waves 6-7 skip A staging (only 4 outstanding B loads) -> vmcnt(4)
#define BOUNDARY_AG(tail)                                                             \
    if (tail) asm volatile("s_waitcnt vmcnt(0)" ::: "memory");                        \
    else if (wv < 6) asm volatile("s_waitcnt vmcnt(8)" ::: "memory");                 \
    else asm volatile("s_waitcnt vmcnt(4)" ::: "memory");                             \
    __builtin_amdgcn_sched_barrier(0);                                                \
    __builtin_amdgcn_s_barrier();

#define GEMM_LOOP(NT, MC, BND)                                                        \
    for (int tt = 0; tt < (NT); ++tt) {                                               \
        const int cur = tt & 1, nxt = cur ^ 1;                                        \
        const bool tail = (tt >= (NT) - 2);                                           \
        BND(tail);                                                                    \
        RD_A(0, MC); RD_B(0, 0);                                                      \
        if (tt + 1 < (NT)) STAGE_A(nxt, 1, tt + 1);                                   \
        MFMAX(0, MC);                                                                 \
        __builtin_amdgcn_s_barrier();                                                 \
        RD_B(0, 2);                                                                   \
        if (tt + 1 < (NT)) STAGE_B(nxt, 1, tt + 1);                                   \
        MFMAX(2, MC);                                                                 \
        __builtin_amdgcn_s_barrier();                                                 \
        BND(tail);                                                                    \
        RD_A(1, MC); RD_B(1, 0);                                                      \
        if (tt + 2 < (NT)) STAGE_A(cur, 0, tt + 2);                                   \
        MFMAX(0, MC);                                                                 \
        __builtin_amdgcn_s_barrier();                                                 \
        RD_B(1, 2);                                                                   \
        if (tt + 2 < (NT)) STAGE_B(cur, 0, tt + 2);                                   \
        MFMAX(2, MC);                                                                 \
    }

// attgemm loop: waves with all-dead output columns (jlive==false) skip reads+MFMA,
// but keep every barrier / boundary / stage so block-level sync is unchanged.
#define GEMM_LOOP_AG(NT, MC, BND)                                                     \
    for (int tt = 0; tt < (NT); ++tt) {                                               \
        const int cur = tt & 1, nxt = cur ^ 1;                                        \
        const bool tail = (tt >= (NT) - 2);                                           \
        BND(tail);                                                                    \
        if (jlive) { RD_A(0, MC); RD_B(0, 0); }                                       \
        if (tt + 1 < (NT)) STAGE_A(nxt, 1, tt + 1);                                   \
        if (jlive) { MFMAX(0, MC); }                                                  \
        __builtin_amdgcn_s_barrier();                                                 \
        if (jlive) { RD_B(0, 2); }                                                    \
        if (tt + 1 < (NT)) STAGE_B(nxt, 1, tt + 1);                                   \
        if (jlive) { MFMAX(2, MC); }                                                  \
        __builtin_amdgcn_s_barrier();                                                 \
        BND(tail);                                                                    \
        if (jlive) { RD_A(1, MC); RD_B(1, 0); }                                       \
        if (tt + 2 < (NT)) STAGE_A(cur, 0, tt + 2);                                   \
        if (jlive) { MFMAX(0, MC); }                                                  \
        __builtin_amdgcn_s_barrier();                                                 \
        if (jlive) { RD_B(1, 2); }                                                    \
        if (tt + 2 < (NT)) STAGE_B(cur, 0, tt + 2);                                   \
        if (jlive) { MFMAX(2, MC); }                                                  \
    }

#define MK_OFFS(MC, SPAN)                                                             \
    int aoff[MC], boff[4];                                                            \
    _Pragma("unroll")                                                                 \
    for (int m = 0; m < (MC); ++m) {                                                  \
        int R = wrow * (SPAN) + m * 16 + l15;                                         \
        int P = PHYS(R);                                                              \
        aoff[m] = P * 32 + ((hi ^ G2P(P)) * 8);                                       \
    }                                                                                 \
    _Pragma("unroll")                                                                 \
    for (int n = 0; n < 4; ++n) {                                                     \
        int R = wcol * 64 + n * 16 + l15;                                             \
        int P = PHYS(R);                                                              \
        boff[n] = P * 32 + ((hi ^ G2P(P)) * 8);                                       \
    }

// ---------------- K3a: MFMA scores GEMM (8-phase, M=256 tiles, hoisted modulo)
__global__ __launch_bounds__(512, 1) void k_scores(const unsigned short* __restrict__ AF,
                                                   const unsigned short* __restrict__ attw,
                                                   const unsigned short* __restrict__ attb,
                                                   unsigned short* __restrict__ Mbf,
                                                   int nloc) {
    __shared__ __bf16 As[2 * 16384];
    __shared__ __bf16 Bs[2 * 16384];
    const int t = threadIdx.x;
    const int nwg = gridDim.x * gridDim.y;
    const int olid = blockIdx.x + gridDim.x * blockIdx.y;
    const int nid = swz8(olid, nwg);
    const int jt = nid % 11, it = nid / 11;
    const int i0 = it * 256, j0 = jt * 256;
    const int lane = t & 63, wv = t >> 6;
    const int wrow = wv >> 2, wcol = wv & 3;
    const int l15 = lane & 15, hi = lane >> 4;

    f32x4 zero = {0.f, 0.f, 0.f, 0.f};
    f32x4 acc[8][4];
#pragma unroll
    for (int m = 0; m < 8; ++m)
#pragma unroll
        for (int n = 0; n < 4; ++n) acc[m][n] = zero;

    MK_OFFS(8, 128);

    const unsigned short *aB0, *aB1, *bB0, *bB1;
    {
        int P0 = t >> 2, P1 = (t + 512) >> 2;
        int g0 = GLOB(P0), g1 = GLOB(P1);
        int lc0 = (t & 3) ^ G2P(P0), lc1 = (t & 3) ^ G2P(P1);
        int ia0 = i0 + g0; if (ia0 > nloc - 1) ia0 = nloc - 1;
        int ia1 = i0 + g1; if (ia1 > nloc - 1) ia1 = nloc - 1;
        int jb0 = j0 + g0; if (jb0 > NM1_ - 1) jb0 = NM1_ - 1;
        int jb1 = j0 + g1; if (jb1 > NM1_ - 1) jb1 = NM1_ - 1;
        aB0 = AF + (size_t)ia0 * D_ + lc0 * 8;
        aB1 = AF + (size_t)ia1 * D_ + lc1 * 8;
        bB0 = attw + (size_t)jb0 * D_ + lc0 * 8;
        bB1 = attw + (size_t)jb1 * D_ + lc1 * 8;
    }
#define STAGE_A(buf, kh, kt) { \
    GLD16(aB0 + (kt) * 64 + (kh) * 32, As + (buf) * 16384 + (kh) * 8192 + t * 8); \
    GLD16(aB1 + (kt) * 64 + (kh) * 32, As + (buf) * 16384 + (kh) * 8192 + (t + 512) * 8); }
#define STAGE_B(buf, kh, kt) { \
    GLD16(bB0 + (kt) * 64 + (kh) * 32, Bs + (buf) * 16384 + (kh) * 8192 + t * 8); \
    GLD16(bB1 + (kt) * 64 + (kh) * 32, Bs + (buf) * 16384 + (kh) * 8192 + (t + 512) * 8); }

    bf16x8 a[8], b0, b1;
    GEMM_PROLOGUE();
    GEMM_LOOP(11, 8, BOUNDARY);    // D_/64
#undef STAGE_A
#undef STAGE_B

    const int r0 = i0 % N_;   // hoisted: one modulo per thread
#pragma unroll
    for (int m = 0; m < 8; ++m) {
        int db = wrow * 128 + m * 16 + hi * 4;
        int ib = i0 + db;
#pragma unroll
        for (int n = 0; n < 4; ++n) {
            int j = j0 + wcol * 64 + n * 16 + l15;
            if (j < NM1_) {
                float bias = bf2f(attb[j]);
#pragma unroll
                for (int q = 0; q < 4; ++q) {
                    int ii = ib + q;
                    if (ii < nloc) {
                        int r = r0 + db + q;
                        if (r >= N_) r -= N_;
                        int c = j + (j >= r);
                        Mbf[(size_t)ii * PK_ + c] = f2bf(acc[m][n][q] + bias);
                    }
                }
            }
        }
    }
}

// ---------------- K3b: bf16 row softmax IN PLACE (stride PK_, zero pad) + f32 M to d_out
__global__ __launch_bounds__(256) void k_softmax(unsigned short* __restrict__ Mbf,
                                                 float* __restrict__ Mout,
                                                 int row_base) {
    const int il = blockIdx.x;
    const int r = il % N_;
    unsigned short* srow = Mbf + (size_t)il * PK_;
    float* orow = Mout + (size_t)(row_base + il) * N_;
    const int t = threadIdx.x;
    float f[16];
#pragma unroll
    for (int q = 0; q < 2; ++q) {
        int c8 = t + 256 * q;
        if (c8 < N_ / 8) {
            uint4 u = *(const uint4*)(srow + c8 * 8);
            const unsigned short* pu = (const unsigned short*)&u;
#pragma unroll
            for (int e = 0; e < 8; ++e) {
                int c = c8 * 8 + e;
                float v = bf2f(pu[e]);
                f[q * 8 + e] = (c == r) ? -1e30f : v;
            }
        } else {
#pragma unroll
            for (int e = 0; e < 8; ++e) f[q * 8 + e] = -1e30f;
        }
    }
    float m = -1e30f;
#pragma unroll
    for (int q = 0; q < 16; ++q) m = fmaxf(m, f[q]);
#pragma unroll
    for (int off = 32; off >= 1; off >>= 1) m = fmaxf(m, __shfl_xor(m, off, 64));
    __shared__ float red[4];
    if ((t & 63) == 0) red[t >> 6] = m;
    __syncthreads();
    m = fmaxf(fmaxf(red[0], red[1]), fmaxf(red[2], red[3]));

    float s = 0.f;
#pragma unroll
    for (int q = 0; q < 16; ++q) { float e = __expf(f[q] - m); f[q] = e; s += e; }
#pragma unroll
    for (int off = 32; off >= 1; off >>= 1) s += __shfl_xor(s, off, 64);
    __shared__ float red2[4];
    if ((t & 63) == 0) red2[t >> 6] = s;
    __syncthreads();
    s = red2[0] + red2[1] + red2[2] + red2[3];
    float inv = 1.0f / s;
#pragma unroll
    for (int q = 0; q < 2; ++q) {
        int c8 = t + 256 * q;
        if (c8 < N_ / 8) {
            float o[8];
            union { unsigned short u[8]; uint4 v; } pb;
#pragma unroll
            for (int e = 0; e < 8; ++e) {
                o[e] = f[q * 8 + e] * inv;     // diag: exp(-1e30-m)=0 -> exact 0
                pb.u[e] = f2bf(o[e]);
            }
            float4 o0 = {o[0], o[1], o[2], o[3]};
            float4 o1 = {o[4], o[5], o[6], o[7]};
            *(float4*)(orow + c8 * 8) = o0;
            *(float4*)(orow + c8 * 8 + 4) = o1;
            *(uint4*)(srow + c8 * 8) = pb.v;
        }
    }
    if (t < 4) {
        uint4 z = {0u, 0u, 0u, 0u};
        *(uint4*)(srow + N_ + t * 8) = z;
    }
}

// ---------------- K4: MFMA att_feat = Mbf @ AF (8-phase, M=192, trimmed A staging,
//                      dead-N-column wave skip for jt==2 / wcol==3)
__global__ __launch_bounds__(512, 1) void k_attgemm(const unsigned short* __restrict__ Mbf,
                                                    const unsigned short* __restrict__ AFT,
                                                    unsigned short* __restrict__ ATF) {
    __shared__ __bf16 As[2 * 16384];
    __shared__ __bf16 Bs[2 * 16384];
    const int t = threadIdx.x;
    const int nwg = gridDim.x * gridDim.y * gridDim.z;
    const int olid = blockIdx.x + gridDim.x * (blockIdx.y + gridDim.y * blockIdx.z);
    const int nid = swz8(olid, nwg);
    const int jt = nid % 3, it = (nid / 3) % 15, bl = nid / 45;
    const int i0 = it * 192, j0 = jt * 256;
    const int lane = t & 63, wv = t >> 6;
    const int wrow = wv >> 2, wcol = wv & 3;
    const int l15 = lane & 15, hi = lane >> 4;
    const bool jlive = (j0 + wcol * 64) < D_;   // wave-uniform: false only jt==2,wcol==3

    f32x4 zero = {0.f, 0.f, 0.f, 0.f};
    f32x4 acc[6][4];
#pragma unroll
    for (int m = 0; m < 6; ++m)
#pragma unroll
        for (int n = 0; n < 4; ++n) acc[m][n] = zero;

    MK_OFFS(6, 96);

    const unsigned short *aB0, *aB1, *bB0, *bB1;
    {
        int P0 = t >> 2, P1 = (t + 512) >> 2;
        int g0 = GLOB(P0), g1 = GLOB(P1);
        int lc0 = (t & 3) ^ G2P(P0), lc1 = (t & 3) ^ G2P(P1);
        int ia0 = i0 + g0; if (ia0 > N_ - 1) ia0 = N_ - 1;
        int ia1 = i0 + g1; if (ia1 > N_ - 1) ia1 = N_ - 1;
        int jb0 = j0 + g0; if (jb0 > D_ - 1) jb0 = D_ - 1;
        int jb1 = j0 + g1; if (jb1 > D_ - 1) jb1 = D_ - 1;
        aB0 = Mbf + ((size_t)bl * N_ + ia0) * PK_ + lc0 * 8;
        aB1 = Mbf + ((size_t)bl * N_ + ia1) * PK_ + lc1 * 8;
        bB0 = AFT + ((size_t)bl * D_ + jb0) * PK_ + lc0 * 8;
        bB1 = AFT + ((size_t)bl * D_ + jb1) * PK_ + lc1 * 8;
    }
// A rows 192..255 unused at M=192 -> phys rows [96,128)+[224,256) -> exactly slots
// t>=384 in both stage calls; waves 6-7 skip A entirely (wave-uniform skip).
#define STAGE_A(buf, kh, kt) { if (t < 384) { \
    GLD16(aB0 + (kt) * 64 + (kh) * 32, As + (buf) * 16384 + (kh) * 8192 + t * 8); \
    GLD16(aB1 + (kt) * 64 + (kh) * 32, As + (buf) * 16384 + (kh) * 8192 + (t + 512) * 8); } }
#define STAGE_B(buf, kh, kt) { \
    GLD16(bB0 + (kt) * 64 + (kh) * 32, Bs + (buf) * 16384 + (kh) * 8192 + t * 8); \
    GLD16(bB1 + (kt) * 64 + (kh) * 32, Bs + (buf) * 16384 + (kh) * 8192 + (t + 512) * 8); }

    bf16x8 a[6], b0, b1;
    GEMM_PROLOGUE();
    GEMM_LOOP_AG(44, 6, BOUNDARY_AG);  // PK_/64
#undef STAGE_A
#undef STAGE_B

    if (jlive) {
#pragma unroll
        for (int m = 0; m < 6; ++m) {
            int rb = i0 + wrow * 96 + m * 16 + hi * 4;
#pragma unroll
            for (int n = 0; n < 4; ++n) {
                int d = j0 + wcol * 64 + n * 16 + l15;
                if (d < D_) {
#pragma unroll
                    for (int q = 0; q < 4; ++q) {
                        int rr = rb + q;
                        if (rr < N_)
                            ATF[((size_t)(bl * N_ + rr)) * D_ + d] = f2bf(acc[m][n][q]);
                    }
                }
            }
        }
    }
}

// ---------------- K5: MFMA heads + fused props epilogue (f32 out)
__global__ __launch_bounds__(256) void k_head(const unsigned short* __restrict__ ATF,
                                              const unsigned short* __restrict__ AF,
                                              const unsigned short* __restrict__ clsw,
                                              const unsigned short* __restrict__ clsb,
                                              const unsigned short* __restrict__ regw,
                                              const unsigned short* __restrict__ regb,
                                              const unsigned short* __restrict__ anch,
                                              float* __restrict__ props,
                                              int row_base, int nloc) {
    __shared__ __bf16 As2[128 * 32];
    __shared__ __bf16 Ws[80 * 32];
    const int t = threadIdx.x;
    const int i0 = blockIdx.x * 128;
    const int lane = t & 63, wv = t >> 6;
    const int l15 = lane & 15, hi8 = (lane >> 4) * 8;

    f32x4 zero = {0.f, 0.f, 0.f, 0.f};
    f32x4 acc[2][5];
#pragma unroll
    for (int m = 0; m < 2; ++m)
#pragma unroll
        for (int n = 0; n < 5; ++n) acc[m][n] = zero;

    const int s0 = t, s1 = t + 256;
    const int ar0 = s0 >> 2, ac0 = (s0 & 3) * 8;
    const int ar1 = s1 >> 2, ac1 = (s1 & 3) * 8;
    int ir0 = i0 + ar0; if (ir0 > nloc - 1) ir0 = nloc - 1;
    int ir1 = i0 + ar1; if (ir1 > nloc - 1) ir1 = nloc - 1;
    const unsigned short* w0base = (ar0 < 2) ? (clsw + (size_t)ar0 * D2_)
                                             : (regw + (size_t)(ar0 - 2) * D2_);
    int r1 = 64 + (t >> 2);
    int rc = r1 < 75 ? r1 : 74;
    const unsigned short* w1base = regw + (size_t)(rc - 2) * D2_;
    const int w1c = (t & 3) * 8;

    for (int p = 0; p < 2; ++p) {
        const unsigned short* Asrc = (p == 0) ? ATF : AF;
        const int wcol = p * D_;
        for (int k0 = 0; k0 < D_; k0 += 32) {
            GLD16(Asrc + (size_t)ir0 * D_ + ac0 + k0, As2 + s0 * 8);
            GLD16(Asrc + (size_t)ir1 * D_ + ac1 + k0, As2 + s1 * 8);
            GLD16(w0base + wcol + k0 + ac0, Ws + s0 * 8);
            if (t < 64) GLD16(w1base + wcol + k0 + w1c, Ws + (size_t)(256 + t) * 8);
            __syncthreads();
            bf16x8 a[2], bb[5];
#pragma unroll
            for (int m = 0; m < 2; ++m)
                a[m] = *(const bf16x8*)(As2 + (wv * 32 + m * 16 + l15) * 32 + hi8);
#pragma unroll
            for (int n = 0; n < 5; ++n)
                bb[n] = *(const bf16x8*)(Ws + (n * 16 + l15) * 32 + hi8);
#pragma unroll
            for (int m = 0; m < 2; ++m)
#pragma unroll
                for (int n = 0; n < 5; ++n)
                    acc[m][n] = __builtin_amdgcn_mfma_f32_16x16x32_bf16(a[m], bb[n], acc[m][n], 0, 0, 0);
            __syncthreads();
        }
    }

#pragma unroll
    for (int m = 0; m < 2; ++m) {
        int ib = i0 + wv * 32 + m * 16 + (lane >> 4) * 4;
#pragma unroll
        for (int n = 0; n < 5; ++n) {
            int j = n * 16 + l15;
            if (j < 75) {
#pragma unroll
                for (int q = 0; q < 4; ++q) {
                    int i = ib + q;
                    if (i < nloc) {
                        size_t g = (size_t)(row_base + i);
                        int nn = i % N_;
                        float v = acc[m][n][q];
                        if (j < 2) {
                            props[g * PW_ + j] = v + bf2f(clsb[j]);
                            props[g * PW_ + 2 + j] = bf2f(anch[(size_t)nn * PW_ + 2 + j]);
                        } else {
                            int tt = j - 2;
                            props[g * PW_ + 4 + tt] = v + bf2f(regb[tt]) + bf2f(anch[(size_t)nn * PW_ + 4 + tt]);
                        }
                    }
                }
            }
        }
    }
}

extern "C" void kernel_launch(void* const* d_in, const int* in_sizes, int n_in,
                              void* d_out, int out_size, void* d_ws, size_t ws_size,
                              hipStream_t stream) {
    (void)in_sizes; (void)n_in; (void)out_size;

    float* props = (float*)d_out;
    float* Mbuf  = props + (size_t)ROWS_ * PW_;

    char* ws = (char*)d_ws;
    int* flags = (int*)(ws + OFF_FLAGS);
    float* feat = (float*)(ws + OFF_FEAT);
    char* canon = ws + OFF_CANON;
    unsigned short* cx    = (unsigned short*)(canon + C_X);
    unsigned short* cattw = (unsigned short*)(canon + C_ATTW);
    unsigned short* ccw   = (unsigned short*)(canon + C_CW);
    unsigned short* canch = (unsigned short*)(canon + C_ANCH);
    unsigned short* cclsw = (unsigned short*)(canon + C_CLSW);
    unsigned short* cregw = (unsigned short*)(canon + C_REGW);
    unsigned short* ccb   = (unsigned short*)(canon + C_CB);
    unsigned short* cattb = (unsigned short*)(canon + C_ATTB);
    unsigned short* cclsb = (unsigned short*)(canon + C_CLSB);
    unsigned short* cregb = (unsigned short*)(canon + C_REGB);
    int* ccut = (int*)(canon + C_CUT);
    int* cmsk = (int*)(canon + C_MASK);

    const size_t base = (size_t)(12u << 20);
    const size_t per  = ((size_t)N_ * D_ * 2) * 2 + (size_t)D_ * PK_ * 2 + (size_t)N_ * PK_ * 2;
    int CN = 1;
    for (int c = 16; c >= 1; c >>= 1)
        if (ws_size >= base + (size_t)c * per) { CN = c; break; }
    unsigned short* AF  = (unsigned short*)(ws + base);
    unsigned short* AFT = AF  + (size_t)CN * N_ * D_;
    unsigned short* ATF = AFT + (size_t)CN * D_ * PK_;
    unsigned short* Mbf = ATF + (size_t)CN * N_ * D_;

    k_detect<<<dim3(1), dim3(256), 0, stream>>>((const unsigned int*)d_in[3],
                                                (const unsigned int*)d_in[10],
                                                (const unsigned int*)d_in[11], flags);
    k_canon_f<<<dim3(1024), dim3(256), 0, stream>>>(d_in[0], d_in[1], d_in[2], d_in[3], d_in[4],
                                                    d_in[5], d_in[6], d_in[7], d_in[8], d_in[9],
                                                    canon, flags);
    k_canon_i<<<dim3(120), dim3(256), 0, stream>>>(d_in[10], d_in[11], canon, flags);
    k_conv<<<dim3(880), dim3(256), 0, stream>>>(cx, ccw, ccb, feat);

    const int nchunk = 16 / CN;
    for (int c = 0; c < nchunk; ++c) {
        const int bb = c * CN;
        const int rb = bb * N_;
        const int nl = CN * N_;
        const int it128 = (nl + 127) / 128;
        const int it256 = (nl + 255) / 256;
        const int at192 = (N_ + 191) / 192;   // 15
        k_gather_af<<<dim3(N_, CN), dim3(256), 0, stream>>>(feat, ccut, cmsk, AF, bb);
        k_gather_aft<<<dim3(D_, CN), dim3(256), 0, stream>>>(feat, ccut, cmsk, AFT, bb);
        k_scores<<<dim3(11, it256), dim3(512), 0, stream>>>(AF, cattw, cattb, Mbf, nl);
        k_softmax<<<dim3(nl), dim3(256), 0, stream>>>(Mbf, Mbuf, rb);
        k_attgemm<<<dim3(3, at192, CN), dim3(512), 0, stream>>>(Mbf, AFT, ATF);
        k_head<<<dim3(it128), dim3(256), 0, stream>>>(ATF, AF, cclsw, cclsb, cregw, cregb,
                                                      canch, props, rb, nl);
    }
}